// Round 3
// baseline (1502.747 us; speedup 1.0000x reference)
//
#include <hip/hip_runtime.h>
#include <stdint.h>

#define MEM 512
#define TAGD 100
#define WORD 300
#define TREE_DEPTH 14
#define LEAVES 16384
#define KLEAF 400
#define KP_LEAF 416
#define KCH 712
#define KP_CH 736
#define T2W 224   // tag_child(100) | tag_parent(100) | zero pad(24)

typedef __attribute__((ext_vector_type(8))) short short8;
typedef __attribute__((ext_vector_type(4))) float floatx4;

__device__ __forceinline__ float b2f(unsigned short u) {
    union { unsigned int i; float f; } v; v.i = ((unsigned int)u) << 16; return v.f;
}
__device__ __forceinline__ unsigned short f2b(float f) {
    union { float f; unsigned int i; } v; v.f = f;
    unsigned int r = v.i + 0x7FFFu + ((v.i >> 16) & 1u);
    return (unsigned short)(r >> 16);
}
__device__ __forceinline__ float sigm(float x) { return 1.0f / (1.0f + __expf(-x)); }
__device__ __forceinline__ float tanh_f(float x) { return 1.0f - 2.0f / (__expf(2.0f * x) + 1.0f); }

// ---------------- dtype detection ----------------
// If inputs are fp32 read as u16, mantissa halves hit bf16 inf/NaN bit patterns
// (exp field 0xFF) with p=2^-8 per element -> certain detection. True-bf16
// random data (N(0,1), U(+-0.044)) never has exp 0xFF.

__global__ void init_flag_kernel(int* flag) {
    if (blockIdx.x == 0 && threadIdx.x == 0) *flag = 0;
}

__global__ void detect_kernel(const unsigned short* __restrict__ embs_u,
                              const unsigned short* __restrict__ chwi_u,
                              int* __restrict__ flag) {
    int tid = blockIdx.x * blockDim.x + threadIdx.x;
    int nth = gridDim.x * blockDim.x;
    int found = 0;
    for (int i = tid; i < LEAVES * WORD; i += nth) {
        if (((embs_u[i] >> 7) & 0xFF) == 0xFF) { found = 1; break; }
    }
    if (!found) {
        for (int i = tid; i < 1536 * KCH; i += nth) {
            if (((chwi_u[i] >> 7) & 0xFF) == 0xFF) { found = 1; break; }
        }
    }
    if (found) atomicOr(flag, 1);
}

__device__ __forceinline__ unsigned short ld_bf(int f, const void* p, int i) {
    return f ? f2b(((const float*)p)[i]) : ((const unsigned short*)p)[i];
}
__device__ __forceinline__ float ld_f32(int f, const void* p, int i) {
    return f ? ((const float*)p)[i] : b2f(((const unsigned short*)p)[i]);
}

// ---------------- conversion / packing ----------------

// Weights -> padded bf16 ws copies; biases -> fp32 [6][1536]: lbi,lbh,cbi,cbh,nbi,nbh
__global__ void convert_kernel(const int* __restrict__ flag,
                               const void* leaf_Wi, const void* ch_Wi,
                               const void* ch_Wh, const void* node_Wh,
                               const void* lbi, const void* lbh,
                               const void* cbi, const void* cbh,
                               const void* nbi, const void* nbh,
                               unsigned short* __restrict__ Wl,
                               unsigned short* __restrict__ Wc,
                               unsigned short* __restrict__ Whc,
                               unsigned short* __restrict__ Whn,
                               float* __restrict__ biasf) {
    int f = *flag;
    int tid = blockIdx.x * blockDim.x + threadIdx.x;
    int nth = gridDim.x * blockDim.x;
    for (int idx = tid; idx < 1536 * KP_LEAF; idx += nth) {
        int r = idx / KP_LEAF, c = idx % KP_LEAF;
        Wl[idx] = (c < KLEAF) ? ld_bf(f, leaf_Wi, r * KLEAF + c) : (unsigned short)0;
    }
    for (int idx = tid; idx < 1536 * KP_CH; idx += nth) {
        int r = idx / KP_CH, c = idx % KP_CH;
        Wc[idx] = (c < KCH) ? ld_bf(f, ch_Wi, r * KCH + c) : (unsigned short)0;
    }
    for (int idx = tid; idx < 1536 * MEM; idx += nth) Whc[idx] = ld_bf(f, ch_Wh, idx);
    for (int idx = tid; idx < 1536 * MEM; idx += nth) Whn[idx] = ld_bf(f, node_Wh, idx);
    for (int i = tid; i < 1536; i += nth) {
        biasf[i]            = ld_f32(f, lbi, i);
        biasf[1536 + i]     = ld_f32(f, lbh, i);
        biasf[2 * 1536 + i] = ld_f32(f, cbi, i);
        biasf[3 * 1536 + i] = ld_f32(f, cbh, i);
        biasf[4 * 1536 + i] = ld_f32(f, nbi, i);
        biasf[5 * 1536 + i] = ld_f32(f, nbh, i);
    }
}

// X_leaf[i] = [embs[i](300), tags[L-1+i](100), zeros(16)] -> bf16 [16384 x 416]
__global__ void pack_xleaf_kernel(const int* __restrict__ flag,
                                  const void* embs, const void* tags,
                                  unsigned short* __restrict__ X) {
    int f = *flag;
    int tid = blockIdx.x * blockDim.x + threadIdx.x;
    int nth = gridDim.x * blockDim.x;
    for (int idx = tid; idx < LEAVES * KP_LEAF; idx += nth) {
        int i = idx / KP_LEAF, c = idx % KP_LEAF;
        unsigned short v;
        if (c < WORD) v = ld_bf(f, embs, i * WORD + c);
        else if (c < WORD + TAGD) v = ld_bf(f, tags, (LEAVES - 1 + i) * TAGD + (c - WORD));
        else v = 0;
        X[idx] = v;
    }
}

// T2 rows [0,2n): r<n -> left child of p=(n-1)+r, else right child of p=(n-1)+(r-n)
__global__ void pack_t2_kernel(const int* __restrict__ flag,
                               const void* tags,
                               unsigned short* __restrict__ T2, int n) {
    int f = *flag;
    int tid = blockIdx.x * blockDim.x + threadIdx.x;
    int nth = gridDim.x * blockDim.x;
    int total = 2 * n * T2W;
    for (int idx = tid; idx < total; idx += nth) {
        int r = idx / T2W, c = idx % T2W;
        int half = (r >= n) ? 1 : 0;
        int i = half ? (r - n) : r;
        int p = (n - 1) + i;
        int child = 2 * p + 1 + half;
        unsigned short v;
        if (c < TAGD) v = ld_bf(f, tags, child * TAGD + c);
        else if (c < 2 * TAGD) v = ld_bf(f, tags, p * TAGD + (c - TAGD));
        else v = 0;
        T2[idx] = v;
    }
}

// ---------------- GEMM kernels ----------------
// out = X @ W^T over 3 gates; block = 64 rows x 64 cols; wave wv -> 16 cols.
// A frag: row=lane&15, k=quad*8+j (contig). C/D: col=lane&15, row=quad*4+reg.

__launch_bounds__(256)
__global__ void gemm_leaf(const unsigned short* __restrict__ X,
                          const unsigned short* __restrict__ W,   // Wl [1536 x 416]
                          const float* __restrict__ biasf,        // +0: bi, +1536: bh
                          unsigned short* __restrict__ out) {
    int wv = threadIdx.x >> 6, lane = threadIdx.x & 63;
    int l15 = lane & 15, quad = lane >> 4, koff = quad * 8;
    int m_blk = blockIdx.x * 64;
    int jb = blockIdx.y * 64 + wv * 16;

    floatx4 acc[4][3];
#pragma unroll
    for (int s = 0; s < 4; s++)
#pragma unroll
        for (int g = 0; g < 3; g++) acc[s][g] = (floatx4){0.f, 0.f, 0.f, 0.f};

    for (int kb = 0; kb < KP_LEAF; kb += 32) {
        int k0 = kb + koff;
        short8 a[4];
#pragma unroll
        for (int s = 0; s < 4; s++)
            a[s] = *(const short8*)(X + (size_t)(m_blk + s * 16 + l15) * KP_LEAF + k0);
        short8 b[3];
#pragma unroll
        for (int g = 0; g < 3; g++)
            b[g] = *(const short8*)(W + (size_t)(jb + l15 + g * 512) * KP_LEAF + k0);
#pragma unroll
        for (int s = 0; s < 4; s++)
#pragma unroll
            for (int g = 0; g < 3; g++)
                acc[s][g] = __builtin_amdgcn_mfma_f32_16x16x32_bf16(a[s], b[g], acc[s][g], 0, 0, 0);
    }

    int j = jb + l15;
    float bir = biasf[j], biz = biasf[512 + j], bin = biasf[1024 + j];
    float bhr = biasf[1536 + j], bhz = biasf[2048 + j], bhn = biasf[2560 + j];
#pragma unroll
    for (int s = 0; s < 4; s++)
#pragma unroll
        for (int r = 0; r < 4; r++) {
            int m = m_blk + s * 16 + quad * 4 + r;
            float rr = sigm(acc[s][0][r] + bir + bhr);
            float zz = sigm(acc[s][1][r] + biz + bhz);
            float nn = tanh_f(acc[s][2][r] + bin + rr * bhn);
            out[(size_t)m * MEM + j] = f2b((1.0f - zz) * nn);
        }
}

// Stage 1: h1 = GRU(xl, 0). A gathered: k<512 from states[2n-1+2m], else T2 row m.
__launch_bounds__(256)
__global__ void gemm_stage1(const unsigned short* __restrict__ states,
                            const unsigned short* __restrict__ T2,
                            const unsigned short* __restrict__ Wi,  // Wc [1536 x 736]
                            const float* __restrict__ biasf,        // +2*1536 cbi, +3*1536 cbh
                            int n,
                            unsigned short* __restrict__ h1b,
                            float* __restrict__ h1f) {
    int wv = threadIdx.x >> 6, lane = threadIdx.x & 63;
    int l15 = lane & 15, quad = lane >> 4, koff = quad * 8;
    int m_blk = blockIdx.x * 64;
    int jb = blockIdx.y * 64 + wv * 16;

    floatx4 acc[4][3];
#pragma unroll
    for (int s = 0; s < 4; s++)
#pragma unroll
        for (int g = 0; g < 3; g++) acc[s][g] = (floatx4){0.f, 0.f, 0.f, 0.f};
    short8 z8 = {0, 0, 0, 0, 0, 0, 0, 0};

    for (int kb = 0; kb < KP_CH; kb += 32) {
        int k0 = kb + koff;
        short8 a[4];
#pragma unroll
        for (int s = 0; s < 4; s++) {
            int row = m_blk + s * 16 + l15;
            if (row >= n) a[s] = z8;
            else if (kb < 512)
                a[s] = *(const short8*)(states + (size_t)(2 * n - 1 + 2 * row) * MEM + k0);
            else
                a[s] = *(const short8*)(T2 + (size_t)row * T2W + (k0 - 512));
        }
        short8 b[3];
#pragma unroll
        for (int g = 0; g < 3; g++)
            b[g] = *(const short8*)(Wi + (size_t)(jb + l15 + g * 512) * KP_CH + k0);
#pragma unroll
        for (int s = 0; s < 4; s++)
#pragma unroll
            for (int g = 0; g < 3; g++)
                acc[s][g] = __builtin_amdgcn_mfma_f32_16x16x32_bf16(a[s], b[g], acc[s][g], 0, 0, 0);
    }

    int j = jb + l15;
    float bir = biasf[3072 + j], biz = biasf[3584 + j], bin = biasf[4096 + j];
    float bhr = biasf[4608 + j], bhz = biasf[5120 + j], bhn = biasf[5632 + j];
#pragma unroll
    for (int s = 0; s < 4; s++)
#pragma unroll
        for (int r = 0; r < 4; r++) {
            int m = m_blk + s * 16 + quad * 4 + r;
            if (m >= n) continue;
            float rr = sigm(acc[s][0][r] + bir + bhr);
            float zz = sigm(acc[s][1][r] + biz + bhz);
            float nn = tanh_f(acc[s][2][r] + bin + rr * bhn);
            float h = (1.0f - zz) * nn;
            h1b[(size_t)m * MEM + j] = f2b(h);
            if (h1f) h1f[(size_t)m * MEM + j] = h;
        }
}

// Stage 2: h2 = GRU(xr, h1). Phase 1: gi = xr@Wi^T; phase 2: gh = h1@Wh^T.
__launch_bounds__(256)
__global__ void gemm_stage2(const unsigned short* __restrict__ states,
                            const unsigned short* __restrict__ T2,
                            const unsigned short* __restrict__ Wi,  // Wc
                            const unsigned short* __restrict__ h1b,
                            const float* __restrict__ h1f,
                            const unsigned short* __restrict__ Wh,  // Whc [1536 x 512]
                            const float* __restrict__ biasf,
                            int n,
                            unsigned short* __restrict__ h2b,
                            float* __restrict__ h2f) {
    int wv = threadIdx.x >> 6, lane = threadIdx.x & 63;
    int l15 = lane & 15, quad = lane >> 4, koff = quad * 8;
    int m_blk = blockIdx.x * 64;
    int jb = blockIdx.y * 64 + wv * 16;

    floatx4 gi[4][3], gh[4][3];
#pragma unroll
    for (int s = 0; s < 4; s++)
#pragma unroll
        for (int g = 0; g < 3; g++) {
            gi[s][g] = (floatx4){0.f, 0.f, 0.f, 0.f};
            gh[s][g] = (floatx4){0.f, 0.f, 0.f, 0.f};
        }
    short8 z8 = {0, 0, 0, 0, 0, 0, 0, 0};

    for (int kb = 0; kb < KP_CH; kb += 32) {
        int k0 = kb + koff;
        short8 a[4];
#pragma unroll
        for (int s = 0; s < 4; s++) {
            int row = m_blk + s * 16 + l15;
            if (row >= n) a[s] = z8;
            else if (kb < 512)
                a[s] = *(const short8*)(states + (size_t)(2 * n + 2 * row) * MEM + k0);
            else
                a[s] = *(const short8*)(T2 + (size_t)(n + row) * T2W + (k0 - 512));
        }
        short8 b[3];
#pragma unroll
        for (int g = 0; g < 3; g++)
            b[g] = *(const short8*)(Wi + (size_t)(jb + l15 + g * 512) * KP_CH + k0);
#pragma unroll
        for (int s = 0; s < 4; s++)
#pragma unroll
            for (int g = 0; g < 3; g++)
                gi[s][g] = __builtin_amdgcn_mfma_f32_16x16x32_bf16(a[s], b[g], gi[s][g], 0, 0, 0);
    }

    for (int kb = 0; kb < MEM; kb += 32) {
        int k0 = kb + koff;
        short8 a[4];
#pragma unroll
        for (int s = 0; s < 4; s++) {
            int row = m_blk + s * 16 + l15;
            a[s] = (row < n) ? *(const short8*)(h1b + (size_t)row * MEM + k0) : z8;
        }
        short8 b[3];
#pragma unroll
        for (int g = 0; g < 3; g++)
            b[g] = *(const short8*)(Wh + (size_t)(jb + l15 + g * 512) * MEM + k0);
#pragma unroll
        for (int s = 0; s < 4; s++)
#pragma unroll
            for (int g = 0; g < 3; g++)
                gh[s][g] = __builtin_amdgcn_mfma_f32_16x16x32_bf16(a[s], b[g], gh[s][g], 0, 0, 0);
    }

    int j = jb + l15;
    float bir = biasf[3072 + j], biz = biasf[3584 + j], bin = biasf[4096 + j];
    float bhr = biasf[4608 + j], bhz = biasf[5120 + j], bhn = biasf[5632 + j];
#pragma unroll
    for (int s = 0; s < 4; s++)
#pragma unroll
        for (int r = 0; r < 4; r++) {
            int m = m_blk + s * 16 + quad * 4 + r;
            if (m >= n) continue;
            float hp = h1f ? h1f[(size_t)m * MEM + j] : b2f(h1b[(size_t)m * MEM + j]);
            float rr = sigm(gi[s][0][r] + bir + gh[s][0][r] + bhr);
            float zz = sigm(gi[s][1][r] + biz + gh[s][1][r] + bhz);
            float nn = tanh_f(gi[s][2][r] + bin + rr * (gh[s][2][r] + bhn));
            float h = (1.0f - zz) * nn + zz * hp;
            h2b[(size_t)m * MEM + j] = f2b(h);
            if (h2f) h2f[(size_t)m * MEM + j] = h;
        }
}

// Stage 3: st = GRU(0, h2): gi = node_bi, gh = h2@node_Wh^T + node_bh.
__launch_bounds__(256)
__global__ void gemm_stage3(const unsigned short* __restrict__ h2b,
                            const float* __restrict__ h2f,
                            const unsigned short* __restrict__ Wh,   // Whn
                            const float* __restrict__ biasf,         // +4*1536 nbi, +5*1536 nbh
                            int n,
                            unsigned short* __restrict__ out,
                            float* __restrict__ outf) {
    int wv = threadIdx.x >> 6, lane = threadIdx.x & 63;
    int l15 = lane & 15, quad = lane >> 4, koff = quad * 8;
    int m_blk = blockIdx.x * 64;
    int jb = blockIdx.y * 64 + wv * 16;

    floatx4 acc[4][3];
#pragma unroll
    for (int s = 0; s < 4; s++)
#pragma unroll
        for (int g = 0; g < 3; g++) acc[s][g] = (floatx4){0.f, 0.f, 0.f, 0.f};
    short8 z8 = {0, 0, 0, 0, 0, 0, 0, 0};

    for (int kb = 0; kb < MEM; kb += 32) {
        int k0 = kb + koff;
        short8 a[4];
#pragma unroll
        for (int s = 0; s < 4; s++) {
            int row = m_blk + s * 16 + l15;
            a[s] = (row < n) ? *(const short8*)(h2b + (size_t)row * MEM + k0) : z8;
        }
        short8 b[3];
#pragma unroll
        for (int g = 0; g < 3; g++)
            b[g] = *(const short8*)(Wh + (size_t)(jb + l15 + g * 512) * MEM + k0);
#pragma unroll
        for (int s = 0; s < 4; s++)
#pragma unroll
            for (int g = 0; g < 3; g++)
                acc[s][g] = __builtin_amdgcn_mfma_f32_16x16x32_bf16(a[s], b[g], acc[s][g], 0, 0, 0);
    }

    int j = jb + l15;
    float gir = biasf[6144 + j], giz = biasf[6656 + j], gin = biasf[7168 + j];
    float bhr = biasf[7680 + j], bhz = biasf[8192 + j], bhn = biasf[8704 + j];
#pragma unroll
    for (int s = 0; s < 4; s++)
#pragma unroll
        for (int r = 0; r < 4; r++) {
            int m = m_blk + s * 16 + quad * 4 + r;
            if (m >= n) continue;
            float hp = h2f ? h2f[(size_t)m * MEM + j] : b2f(h2b[(size_t)m * MEM + j]);
            float rr = sigm(gir + acc[s][0][r] + bhr);
            float zz = sigm(giz + acc[s][1][r] + bhz);
            float nn = tanh_f(gin + rr * (acc[s][2][r] + bhn));
            float h = (1.0f - zz) * nn + zz * hp;
            out[(size_t)m * MEM + j] = f2b(h);
            if (outf) outf[(size_t)m * MEM + j] = h;
        }
}

__global__ void copy_out_kernel(const int* __restrict__ flag,
                                const unsigned short* __restrict__ states,
                                const float* __restrict__ rootf,
                                void* __restrict__ out) {
    int j = threadIdx.x;
    if (j >= MEM) return;
    if (*flag) ((float*)out)[j] = rootf[j];
    else ((unsigned short*)out)[j] = states[j];
}

// ---------------- launch ----------------

extern "C" void kernel_launch(void* const* d_in, const int* in_sizes, int n_in,
                              void* d_out, int out_size, void* d_ws, size_t ws_size,
                              hipStream_t stream) {
    const void* embs    = d_in[0];
    const void* tags    = d_in[1];
    const void* leaf_Wi = d_in[2];
    const void* leaf_bi = d_in[4];
    const void* leaf_bh = d_in[5];
    const void* node_Wh = d_in[7];
    const void* node_bi = d_in[8];
    const void* node_bh = d_in[9];
    const void* ch_Wi   = d_in[10];
    const void* ch_Wh   = d_in[11];
    const void* ch_bi   = d_in[12];
    const void* ch_bh   = d_in[13];
    (void)in_sizes; (void)n_in; (void)out_size;

    char* ws = (char*)d_ws;
    const size_t o_flag   = 0;
    const size_t o_bias   = 256;                                   // 6*1536*4 = 36864
    const size_t o_Wl     = o_bias + 37120 - 256;                  // 37120
    const size_t o_Wc     = o_Wl + (size_t)1536 * KP_LEAF * 2;     // +1277952 = 1315072
    const size_t o_Whc    = o_Wc + (size_t)1536 * KP_CH * 2;       // +2260992 = 3576064
    const size_t o_Whn    = o_Whc + (size_t)1536 * MEM * 2;        // +1572864 = 5148928
    const size_t o_states = o_Whn + (size_t)1536 * MEM * 2;        // 6721792
    const size_t o_T2     = o_states + (size_t)32768 * MEM * 2;    // 40276224
    const size_t o_h1b    = o_T2 + (size_t)LEAVES * T2W * 2;       // 47616256
    const size_t o_h2b    = o_h1b + (size_t)8192 * MEM * 2;        // 56004864
    const size_t o_rootf  = o_h2b + (size_t)8192 * MEM * 2;        // 64393472
    const size_t o_h1f    = o_rootf + 2048;                        // 64395520 = NEED1
    const size_t o_h2f    = o_h1f + (size_t)8192 * MEM * 4;        // 81172736
    const size_t NEED0    = o_h2f + (size_t)8192 * MEM * 4;        // 97949952

    bool tier0 = (ws_size >= NEED0);

    int*            flag   = (int*)(ws + o_flag);
    float*          biasf  = (float*)(ws + o_bias);
    unsigned short* Wl     = (unsigned short*)(ws + o_Wl);
    unsigned short* Wc     = (unsigned short*)(ws + o_Wc);
    unsigned short* Whc    = (unsigned short*)(ws + o_Whc);
    unsigned short* Whn    = (unsigned short*)(ws + o_Whn);
    unsigned short* states = (unsigned short*)(ws + o_states);
    unsigned short* T2     = (unsigned short*)(ws + o_T2);
    unsigned short* h1b    = (unsigned short*)(ws + o_h1b);
    unsigned short* h2b    = (unsigned short*)(ws + o_h2b);
    float*          rootf  = (float*)(ws + o_rootf);
    float*          h1f    = tier0 ? (float*)(ws + o_h1f) : nullptr;
    float*          h2f    = tier0 ? (float*)(ws + o_h2f) : nullptr;
    // Xleaf overlays [T2, T2+13.63MB) inside T2+h1b (15.73MB): dead before T2/h1b use
    unsigned short* Xleaf  = (unsigned short*)(ws + o_T2);

    init_flag_kernel<<<1, 64, 0, stream>>>(flag);
    detect_kernel<<<2048, 256, 0, stream>>>((const unsigned short*)embs,
                                            (const unsigned short*)ch_Wi, flag);
    convert_kernel<<<2048, 256, 0, stream>>>(flag, leaf_Wi, ch_Wi, ch_Wh, node_Wh,
                                             leaf_bi, leaf_bh, ch_bi, ch_bh,
                                             node_bi, node_bh,
                                             Wl, Wc, Whc, Whn, biasf);
    pack_xleaf_kernel<<<2048, 256, 0, stream>>>(flag, embs, tags, Xleaf);

    {
        dim3 g(LEAVES / 64, 8);
        gemm_leaf<<<g, 256, 0, stream>>>(Xleaf, Wl, biasf,
                                         states + (size_t)(LEAVES - 1) * MEM);
    }

    for (int lvl = TREE_DEPTH - 1; lvl >= 0; lvl--) {
        int n = 1 << lvl;
        int total = 2 * n * T2W;
        int blocks = (total + 255) / 256;
        if (blocks > 2048) blocks = 2048;
        pack_t2_kernel<<<blocks, 256, 0, stream>>>(flag, tags, T2, n);

        dim3 g((n + 63) / 64, 8);
        gemm_stage1<<<g, 256, 0, stream>>>(states, T2, Wc, biasf, n, h1b, h1f);
        gemm_stage2<<<g, 256, 0, stream>>>(states, T2, Wc, h1b, h1f, Whc, biasf,
                                           n, h2b, h2f);
        gemm_stage3<<<g, 256, 0, stream>>>(h2b, h2f, Whn, biasf, n,
                                           states + (size_t)(n - 1) * MEM,
                                           (n == 1) ? rootf : nullptr);
    }

    copy_out_kernel<<<1, 512, 0, stream>>>(flag, states, rootf, d_out);
}

// Round 4
// 1237.775 us; speedup vs baseline: 1.2141x; 1.2141x over previous
//
#include <hip/hip_runtime.h>
#include <stdint.h>

#define MEM 512
#define TAGD 100
#define WORD 300
#define TREE_DEPTH 14
#define LEAVES 16384
#define KLEAF 400
#define KP_LEAF 416
#define KCH 712
#define KP_CH 736
#define T2W 224   // tag_child(100) | tag_parent(100) | pad(24)

typedef __attribute__((ext_vector_type(8))) short short8;
typedef __attribute__((ext_vector_type(4))) float floatx4;

__device__ __forceinline__ float b2f(unsigned short u) {
    union { unsigned int i; float f; } v; v.i = ((unsigned int)u) << 16; return v.f;
}
__device__ __forceinline__ unsigned short f2b(float f) {
    union { float f; unsigned int i; } v; v.f = f;
    unsigned int r = v.i + 0x7FFFu + ((v.i >> 16) & 1u);
    return (unsigned short)(r >> 16);
}
__device__ __forceinline__ float sigm(float x) { return 1.0f / (1.0f + __expf(-x)); }
__device__ __forceinline__ float tanh_f(float x) { return 1.0f - 2.0f / (__expf(2.0f * x) + 1.0f); }

// ---------------- dtype detection (inputs may be fp32 or bf16) ----------------

__global__ void init_flag_kernel(int* flag) {
    if (blockIdx.x == 0 && threadIdx.x == 0) *flag = 0;
}

__global__ void detect_kernel(const unsigned short* __restrict__ embs_u,
                              const unsigned short* __restrict__ chwi_u,
                              int* __restrict__ flag) {
    int tid = blockIdx.x * blockDim.x + threadIdx.x;
    int nth = gridDim.x * blockDim.x;
    int found = 0;
    for (int i = tid; i < LEAVES * WORD; i += nth) {
        if (((embs_u[i] >> 7) & 0xFF) == 0xFF) { found = 1; break; }
    }
    if (!found) {
        for (int i = tid; i < 1536 * KCH; i += nth) {
            if (((chwi_u[i] >> 7) & 0xFF) == 0xFF) { found = 1; break; }
        }
    }
    if (found) atomicOr(flag, 1);
}

__device__ __forceinline__ unsigned short ld_bf(int f, const void* p, int i) {
    return f ? f2b(((const float*)p)[i]) : ((const unsigned short*)p)[i];
}
__device__ __forceinline__ float ld_f32(int f, const void* p, int i) {
    return f ? ((const float*)p)[i] : b2f(((const unsigned short*)p)[i]);
}

// ---------------- conversion / packing ----------------

__global__ void convert_kernel(const int* __restrict__ flag,
                               const void* leaf_Wi, const void* ch_Wi,
                               const void* ch_Wh, const void* node_Wh,
                               const void* lbi, const void* lbh,
                               const void* cbi, const void* cbh,
                               const void* nbi, const void* nbh,
                               unsigned short* __restrict__ Wl,
                               unsigned short* __restrict__ Wc,
                               unsigned short* __restrict__ Whc,
                               unsigned short* __restrict__ Whn,
                               float* __restrict__ biasf) {
    int f = *flag;
    int tid = blockIdx.x * blockDim.x + threadIdx.x;
    int nth = gridDim.x * blockDim.x;
    for (int idx = tid; idx < 1536 * KP_LEAF; idx += nth) {
        int r = idx / KP_LEAF, c = idx % KP_LEAF;
        Wl[idx] = (c < KLEAF) ? ld_bf(f, leaf_Wi, r * KLEAF + c) : (unsigned short)0;
    }
    for (int idx = tid; idx < 1536 * KP_CH; idx += nth) {
        int r = idx / KP_CH, c = idx % KP_CH;
        Wc[idx] = (c < KCH) ? ld_bf(f, ch_Wi, r * KCH + c) : (unsigned short)0;
    }
    for (int idx = tid; idx < 1536 * MEM; idx += nth) Whc[idx] = ld_bf(f, ch_Wh, idx);
    for (int idx = tid; idx < 1536 * MEM; idx += nth) Whn[idx] = ld_bf(f, node_Wh, idx);
    for (int i = tid; i < 1536; i += nth) {
        biasf[i]            = ld_f32(f, lbi, i);
        biasf[1536 + i]     = ld_f32(f, lbh, i);
        biasf[2 * 1536 + i] = ld_f32(f, cbi, i);
        biasf[3 * 1536 + i] = ld_f32(f, cbh, i);
        biasf[4 * 1536 + i] = ld_f32(f, nbi, i);
        biasf[5 * 1536 + i] = ld_f32(f, nbh, i);
    }
}

__global__ void pack_xleaf_kernel(const int* __restrict__ flag,
                                  const void* embs, const void* tags,
                                  unsigned short* __restrict__ X) {
    int f = *flag;
    int tid = blockIdx.x * blockDim.x + threadIdx.x;
    int nth = gridDim.x * blockDim.x;
    for (int idx = tid; idx < LEAVES * KP_LEAF; idx += nth) {
        int i = idx / KP_LEAF, c = idx % KP_LEAF;
        unsigned short v;
        if (c < WORD) v = ld_bf(f, embs, i * WORD + c);
        else if (c < WORD + TAGD) v = ld_bf(f, tags, (LEAVES - 1 + i) * TAGD + (c - WORD));
        else v = 0;
        X[idx] = v;
    }
}

// T2 rows [0,2n): r<n -> left child of p=(n-1)+r, else right child of p=(n-1)+(r-n)
__global__ void pack_t2_kernel(const int* __restrict__ flag,
                               const void* tags,
                               unsigned short* __restrict__ T2, int n) {
    int f = *flag;
    int tid = blockIdx.x * blockDim.x + threadIdx.x;
    int nth = gridDim.x * blockDim.x;
    int total = 2 * n * T2W;
    for (int idx = tid; idx < total; idx += nth) {
        int r = idx / T2W, c = idx % T2W;
        int half = (r >= n) ? 1 : 0;
        int i = half ? (r - n) : r;
        int p = (n - 1) + i;
        int child = 2 * p + 1 + half;
        unsigned short v;
        if (c < TAGD) v = ld_bf(f, tags, child * TAGD + c);
        else if (c < 2 * TAGD) v = ld_bf(f, tags, p * TAGD + (c - TAGD));
        else v = 0;
        T2[idx] = v;
    }
}

// ================= BIG-LEVEL GEMM ENGINE =================
// Tile: 128 rows x 16 j-cols x 3 gates. 256 threads; wave w owns rows
// [m_blk + 32w, m_blk + 32w + 32). W j-slice (48 rows) staged in LDS,
// double-buffered K-chunks of <=256, padded stride 264 elems.
// A frag: row=lane&15, k=quad*8.. ; C/D: col=lane&15, row=quad*4+reg.

struct Chunk {
    const unsigned short* A;   // base, already offset to chunk's k-start
    int astride;               // elements
    int alpha, beta;           // global A row = alpha*m + beta
    const unsigned short* W;   // weight base
    int wstride;               // elements
    int wkb;                   // chunk k-start within W row
    int len;                   // chunk K length (mult of 32, <=256)
};

#define LDSPITCH 264

// MODE: 0 leaf, 1 stage1 (h1=GRU(xl,0)), 2 stage2 (h2=GRU(xr,h1)), 3 stage3 (node)
template<int MODE>
__launch_bounds__(256)
__global__ void big_gemm(const unsigned short* __restrict__ states,
                         const unsigned short* __restrict__ T2,
                         const unsigned short* __restrict__ Xleaf,
                         const unsigned short* __restrict__ Wl,
                         const unsigned short* __restrict__ Wc,
                         const unsigned short* __restrict__ Whc,
                         const unsigned short* __restrict__ Whn,
                         const unsigned short* __restrict__ h1b,
                         const float* __restrict__ h1f,
                         const unsigned short* __restrict__ h2b,
                         const float* __restrict__ h2f,
                         const float* __restrict__ biasf,
                         int n,
                         unsigned short* __restrict__ outb,
                         float* __restrict__ outf) {
    int tid = threadIdx.x;
    int w = tid >> 6, lane = tid & 63, l15 = lane & 15, quad = lane >> 4;
    int m_blk = blockIdx.x * 128;
    int jb = blockIdx.y * 16;

    __shared__ unsigned short lds[2][48 * LDSPITCH];

    Chunk ch[5];
    int nch;
    if (MODE == 0) {
        ch[0] = {Xleaf,        KP_LEAF, 1, 0, Wl, KP_LEAF, 0,   256};
        ch[1] = {Xleaf + 256,  KP_LEAF, 1, 0, Wl, KP_LEAF, 256, 160};
        nch = 2;
    } else if (MODE == 1) {
        ch[0] = {states,       MEM, 2, 2 * n - 1, Wc, KP_CH, 0,   256};
        ch[1] = {states + 256, MEM, 2, 2 * n - 1, Wc, KP_CH, 256, 256};
        ch[2] = {T2,           T2W, 1, 0,         Wc, KP_CH, 512, 224};
        nch = 3;
    } else if (MODE == 2) {
        ch[0] = {states,       MEM, 2, 2 * n,     Wc, KP_CH, 0,   256};
        ch[1] = {states + 256, MEM, 2, 2 * n,     Wc, KP_CH, 256, 256};
        ch[2] = {T2 + (size_t)n * T2W, T2W, 1, 0, Wc, KP_CH, 512, 224};
        ch[3] = {h1b,          MEM, 1, 0,         Whc, MEM, 0,   256};
        ch[4] = {h1b + 256,    MEM, 1, 0,         Whc, MEM, 256, 256};
        nch = 5;
    } else {
        ch[0] = {h2b,          MEM, 1, 0,         Whn, MEM, 0,   256};
        ch[1] = {h2b + 256,    MEM, 1, 0,         Whn, MEM, 256, 256};
        nch = 2;
    }

    floatx4 acc[2][2][3];
#pragma unroll
    for (int a = 0; a < 2; a++)
#pragma unroll
        for (int s = 0; s < 2; s++)
#pragma unroll
            for (int g = 0; g < 3; g++) acc[a][s][g] = (floatx4){0.f, 0.f, 0.f, 0.f};

    auto stage = [&](int c, int buf) {
        const Chunk& k = ch[c];
        int chunks16 = k.len >> 3;            // 16B units per row
        int nslots = 48 * chunks16;
        for (int s1 = tid; s1 < nslots; s1 += 256) {
            int row = s1 / chunks16;
            int kc = s1 - row * chunks16;
            int g = row >> 4, jj = row & 15;
            short8 v = *(const short8*)(k.W + (size_t)(g * 512 + jb + jj) * k.wstride + k.wkb + kc * 8);
            *(short8*)(&lds[buf][row * LDSPITCH + kc * 8]) = v;
        }
    };

    stage(0, 0);

    for (int c = 0; c < nch; c++) {
        __syncthreads();
        if (c + 1 < nch) stage(c + 1, (c + 1) & 1);
        const Chunk& k = ch[c];
        int as = (MODE == 2 && c >= 3) ? 1 : 0;
        const unsigned short* arow0 = k.A + (size_t)(k.alpha * (m_blk + w * 32 + l15) + k.beta) * k.astride + quad * 8;
        const unsigned short* arow1 = k.A + (size_t)(k.alpha * (m_blk + w * 32 + 16 + l15) + k.beta) * k.astride + quad * 8;
        const unsigned short* lb = &lds[c & 1][l15 * LDSPITCH + quad * 8];
#pragma unroll 4
        for (int kk = 0; kk < k.len; kk += 32) {
            short8 a0 = *(const short8*)(arow0 + kk);
            short8 a1 = *(const short8*)(arow1 + kk);
#pragma unroll
            for (int g = 0; g < 3; g++) {
                short8 b = *(const short8*)(lb + g * 16 * LDSPITCH + kk);
                acc[as][0][g] = __builtin_amdgcn_mfma_f32_16x16x32_bf16(a0, b, acc[as][0][g], 0, 0, 0);
                acc[as][1][g] = __builtin_amdgcn_mfma_f32_16x16x32_bf16(a1, b, acc[as][1][g], 0, 0, 0);
            }
        }
    }

    int j = jb + l15;
    if (MODE == 0) {
        float bir = biasf[j], biz = biasf[512 + j], bin = biasf[1024 + j];
        float bhr = biasf[1536 + j], bhz = biasf[2048 + j], bhn = biasf[2560 + j];
#pragma unroll
        for (int s = 0; s < 2; s++)
#pragma unroll
            for (int r = 0; r < 4; r++) {
                int m = m_blk + w * 32 + s * 16 + quad * 4 + r;
                float rr = sigm(acc[0][s][0][r] + bir + bhr);
                float zz = sigm(acc[0][s][1][r] + biz + bhz);
                float nn = tanh_f(acc[0][s][2][r] + bin + rr * bhn);
                outb[(size_t)m * MEM + j] = f2b((1.0f - zz) * nn);
            }
    } else if (MODE == 1) {
        float bir = biasf[3072 + j], biz = biasf[3584 + j], bin = biasf[4096 + j];
        float bhr = biasf[4608 + j], bhz = biasf[5120 + j], bhn = biasf[5632 + j];
#pragma unroll
        for (int s = 0; s < 2; s++)
#pragma unroll
            for (int r = 0; r < 4; r++) {
                int m = m_blk + w * 32 + s * 16 + quad * 4 + r;
                float rr = sigm(acc[0][s][0][r] + bir + bhr);
                float zz = sigm(acc[0][s][1][r] + biz + bhz);
                float nn = tanh_f(acc[0][s][2][r] + bin + rr * bhn);
                float h = (1.0f - zz) * nn;
                outb[(size_t)m * MEM + j] = f2b(h);
                if (outf) outf[(size_t)m * MEM + j] = h;
            }
    } else if (MODE == 2) {
        float bir = biasf[3072 + j], biz = biasf[3584 + j], bin = biasf[4096 + j];
        float bhr = biasf[4608 + j], bhz = biasf[5120 + j], bhn = biasf[5632 + j];
#pragma unroll
        for (int s = 0; s < 2; s++)
#pragma unroll
            for (int r = 0; r < 4; r++) {
                int m = m_blk + w * 32 + s * 16 + quad * 4 + r;
                float hp = h1f ? h1f[(size_t)m * MEM + j] : b2f(h1b[(size_t)m * MEM + j]);
                float rr = sigm(acc[0][s][0][r] + bir + acc[1][s][0][r] + bhr);
                float zz = sigm(acc[0][s][1][r] + biz + acc[1][s][1][r] + bhz);
                float nn = tanh_f(acc[0][s][2][r] + bin + rr * (acc[1][s][2][r] + bhn));
                float h = (1.0f - zz) * nn + zz * hp;
                outb[(size_t)m * MEM + j] = f2b(h);
                if (outf) outf[(size_t)m * MEM + j] = h;
            }
    } else {
        float gir = biasf[6144 + j], giz = biasf[6656 + j], gin = biasf[7168 + j];
        float bhr = biasf[7680 + j], bhz = biasf[8192 + j], bhn = biasf[8704 + j];
#pragma unroll
        for (int s = 0; s < 2; s++)
#pragma unroll
            for (int r = 0; r < 4; r++) {
                int m = m_blk + w * 32 + s * 16 + quad * 4 + r;
                float hp = h2f ? h2f[(size_t)m * MEM + j] : b2f(h2b[(size_t)m * MEM + j]);
                float rr = sigm(gir + acc[0][s][0][r] + bhr);
                float zz = sigm(giz + acc[0][s][1][r] + bhz);
                float nn = tanh_f(gin + rr * (acc[0][s][2][r] + bhn));
                float h = (1.0f - zz) * nn + zz * hp;
                outb[(size_t)m * MEM + j] = f2b(h);
            }
    }
}

// ================= SMALL-LEVEL KERNELS (round-3, proven) =================

__launch_bounds__(256)
__global__ void gemm_stage1(const unsigned short* __restrict__ states,
                            const unsigned short* __restrict__ T2,
                            const unsigned short* __restrict__ Wi,
                            const float* __restrict__ biasf,
                            int n,
                            unsigned short* __restrict__ h1b,
                            float* __restrict__ h1f) {
    int wv = threadIdx.x >> 6, lane = threadIdx.x & 63;
    int l15 = lane & 15, quad = lane >> 4, koff = quad * 8;
    int m_blk = blockIdx.x * 64;
    int jb = blockIdx.y * 64 + wv * 16;

    floatx4 acc[4][3];
#pragma unroll
    for (int s = 0; s < 4; s++)
#pragma unroll
        for (int g = 0; g < 3; g++) acc[s][g] = (floatx4){0.f, 0.f, 0.f, 0.f};
    short8 z8 = {0, 0, 0, 0, 0, 0, 0, 0};

    for (int kb = 0; kb < KP_CH; kb += 32) {
        int k0 = kb + koff;
        short8 a[4];
#pragma unroll
        for (int s = 0; s < 4; s++) {
            int row = m_blk + s * 16 + l15;
            if (row >= n) a[s] = z8;
            else if (kb < 512)
                a[s] = *(const short8*)(states + (size_t)(2 * n - 1 + 2 * row) * MEM + k0);
            else
                a[s] = *(const short8*)(T2 + (size_t)row * T2W + (k0 - 512));
        }
        short8 b[3];
#pragma unroll
        for (int g = 0; g < 3; g++)
            b[g] = *(const short8*)(Wi + (size_t)(jb + l15 + g * 512) * KP_CH + k0);
#pragma unroll
        for (int s = 0; s < 4; s++)
#pragma unroll
            for (int g = 0; g < 3; g++)
                acc[s][g] = __builtin_amdgcn_mfma_f32_16x16x32_bf16(a[s], b[g], acc[s][g], 0, 0, 0);
    }

    int j = jb + l15;
    float bir = biasf[3072 + j], biz = biasf[3584 + j], bin = biasf[4096 + j];
    float bhr = biasf[4608 + j], bhz = biasf[5120 + j], bhn = biasf[5632 + j];
#pragma unroll
    for (int s = 0; s < 4; s++)
#pragma unroll
        for (int r = 0; r < 4; r++) {
            int m = m_blk + s * 16 + quad * 4 + r;
            if (m >= n) continue;
            float rr = sigm(acc[s][0][r] + bir + bhr);
            float zz = sigm(acc[s][1][r] + biz + bhz);
            float nn = tanh_f(acc[s][2][r] + bin + rr * bhn);
            float h = (1.0f - zz) * nn;
            h1b[(size_t)m * MEM + j] = f2b(h);
            if (h1f) h1f[(size_t)m * MEM + j] = h;
        }
}

__launch_bounds__(256)
__global__ void gemm_stage2(const unsigned short* __restrict__ states,
                            const unsigned short* __restrict__ T2,
                            const unsigned short* __restrict__ Wi,
                            const unsigned short* __restrict__ h1b,
                            const float* __restrict__ h1f,
                            const unsigned short* __restrict__ Wh,
                            const float* __restrict__ biasf,
                            int n,
                            unsigned short* __restrict__ h2b,
                            float* __restrict__ h2f) {
    int wv = threadIdx.x >> 6, lane = threadIdx.x & 63;
    int l15 = lane & 15, quad = lane >> 4, koff = quad * 8;
    int m_blk = blockIdx.x * 64;
    int jb = blockIdx.y * 64 + wv * 16;

    floatx4 gi[4][3], gh[4][3];
#pragma unroll
    for (int s = 0; s < 4; s++)
#pragma unroll
        for (int g = 0; g < 3; g++) {
            gi[s][g] = (floatx4){0.f, 0.f, 0.f, 0.f};
            gh[s][g] = (floatx4){0.f, 0.f, 0.f, 0.f};
        }
    short8 z8 = {0, 0, 0, 0, 0, 0, 0, 0};

    for (int kb = 0; kb < KP_CH; kb += 32) {
        int k0 = kb + koff;
        short8 a[4];
#pragma unroll
        for (int s = 0; s < 4; s++) {
            int row = m_blk + s * 16 + l15;
            if (row >= n) a[s] = z8;
            else if (kb < 512)
                a[s] = *(const short8*)(states + (size_t)(2 * n + 2 * row) * MEM + k0);
            else
                a[s] = *(const short8*)(T2 + (size_t)(n + row) * T2W + (k0 - 512));
        }
        short8 b[3];
#pragma unroll
        for (int g = 0; g < 3; g++)
            b[g] = *(const short8*)(Wi + (size_t)(jb + l15 + g * 512) * KP_CH + k0);
#pragma unroll
        for (int s = 0; s < 4; s++)
#pragma unroll
            for (int g = 0; g < 3; g++)
                gi[s][g] = __builtin_amdgcn_mfma_f32_16x16x32_bf16(a[s], b[g], gi[s][g], 0, 0, 0);
    }

    for (int kb = 0; kb < MEM; kb += 32) {
        int k0 = kb + koff;
        short8 a[4];
#pragma unroll
        for (int s = 0; s < 4; s++) {
            int row = m_blk + s * 16 + l15;
            a[s] = (row < n) ? *(const short8*)(h1b + (size_t)row * MEM + k0) : z8;
        }
        short8 b[3];
#pragma unroll
        for (int g = 0; g < 3; g++)
            b[g] = *(const short8*)(Wh + (size_t)(jb + l15 + g * 512) * MEM + k0);
#pragma unroll
        for (int s = 0; s < 4; s++)
#pragma unroll
            for (int g = 0; g < 3; g++)
                gh[s][g] = __builtin_amdgcn_mfma_f32_16x16x32_bf16(a[s], b[g], gh[s][g], 0, 0, 0);
    }

    int j = jb + l15;
    float bir = biasf[3072 + j], biz = biasf[3584 + j], bin = biasf[4096 + j];
    float bhr = biasf[4608 + j], bhz = biasf[5120 + j], bhn = biasf[5632 + j];
#pragma unroll
    for (int s = 0; s < 4; s++)
#pragma unroll
        for (int r = 0; r < 4; r++) {
            int m = m_blk + s * 16 + quad * 4 + r;
            if (m >= n) continue;
            float hp = h1f ? h1f[(size_t)m * MEM + j] : b2f(h1b[(size_t)m * MEM + j]);
            float rr = sigm(gi[s][0][r] + bir + gh[s][0][r] + bhr);
            float zz = sigm(gi[s][1][r] + biz + gh[s][1][r] + bhz);
            float nn = tanh_f(gi[s][2][r] + bin + rr * (gh[s][2][r] + bhn));
            float h = (1.0f - zz) * nn + zz * hp;
            h2b[(size_t)m * MEM + j] = f2b(h);
            if (h2f) h2f[(size_t)m * MEM + j] = h;
        }
}

__launch_bounds__(256)
__global__ void gemm_stage3(const unsigned short* __restrict__ h2b,
                            const float* __restrict__ h2f,
                            const unsigned short* __restrict__ Wh,
                            const float* __restrict__ biasf,
                            int n,
                            unsigned short* __restrict__ out,
                            float* __restrict__ outf) {
    int wv = threadIdx.x >> 6, lane = threadIdx.x & 63;
    int l15 = lane & 15, quad = lane >> 4, koff = quad * 8;
    int m_blk = blockIdx.x * 64;
    int jb = blockIdx.y * 64 + wv * 16;

    floatx4 acc[4][3];
#pragma unroll
    for (int s = 0; s < 4; s++)
#pragma unroll
        for (int g = 0; g < 3; g++) acc[s][g] = (floatx4){0.f, 0.f, 0.f, 0.f};
    short8 z8 = {0, 0, 0, 0, 0, 0, 0, 0};

    for (int kb = 0; kb < MEM; kb += 32) {
        int k0 = kb + koff;
        short8 a[4];
#pragma unroll
        for (int s = 0; s < 4; s++) {
            int row = m_blk + s * 16 + l15;
            a[s] = (row < n) ? *(const short8*)(h2b + (size_t)row * MEM + k0) : z8;
        }
        short8 b[3];
#pragma unroll
        for (int g = 0; g < 3; g++)
            b[g] = *(const short8*)(Wh + (size_t)(jb + l15 + g * 512) * MEM + k0);
#pragma unroll
        for (int s = 0; s < 4; s++)
#pragma unroll
            for (int g = 0; g < 3; g++)
                acc[s][g] = __builtin_amdgcn_mfma_f32_16x16x32_bf16(a[s], b[g], acc[s][g], 0, 0, 0);
    }

    int j = jb + l15;
    float gir = biasf[6144 + j], giz = biasf[6656 + j], gin = biasf[7168 + j];
    float bhr = biasf[7680 + j], bhz = biasf[8192 + j], bhn = biasf[8704 + j];
#pragma unroll
    for (int s = 0; s < 4; s++)
#pragma unroll
        for (int r = 0; r < 4; r++) {
            int m = m_blk + s * 16 + quad * 4 + r;
            if (m >= n) continue;
            float hp = h2f ? h2f[(size_t)m * MEM + j] : b2f(h2b[(size_t)m * MEM + j]);
            float rr = sigm(gir + acc[s][0][r] + bhr);
            float zz = sigm(giz + acc[s][1][r] + bhz);
            float nn = tanh_f(gin + rr * (acc[s][2][r] + bhn));
            float h = (1.0f - zz) * nn + zz * hp;
            out[(size_t)m * MEM + j] = f2b(h);
            if (outf) outf[(size_t)m * MEM + j] = h;
        }
}

__global__ void copy_out_kernel(const int* __restrict__ flag,
                                const unsigned short* __restrict__ states,
                                const float* __restrict__ rootf,
                                void* __restrict__ out) {
    int j = threadIdx.x;
    if (j >= MEM) return;
    if (*flag) ((float*)out)[j] = rootf[j];
    else ((unsigned short*)out)[j] = states[j];
}

// ---------------- launch ----------------

extern "C" void kernel_launch(void* const* d_in, const int* in_sizes, int n_in,
                              void* d_out, int out_size, void* d_ws, size_t ws_size,
                              hipStream_t stream) {
    const void* embs    = d_in[0];
    const void* tags    = d_in[1];
    const void* leaf_Wi = d_in[2];
    const void* leaf_bi = d_in[4];
    const void* leaf_bh = d_in[5];
    const void* node_Wh = d_in[7];
    const void* node_bi = d_in[8];
    const void* node_bh = d_in[9];
    const void* ch_Wi   = d_in[10];
    const void* ch_Wh   = d_in[11];
    const void* ch_bi   = d_in[12];
    const void* ch_bh   = d_in[13];
    (void)in_sizes; (void)n_in; (void)out_size;

    char* ws = (char*)d_ws;
    const size_t o_flag   = 0;
    const size_t o_bias   = 256;
    const size_t o_Wl     = o_bias + 36864;
    const size_t o_Wc     = o_Wl + (size_t)1536 * KP_LEAF * 2;
    const size_t o_Whc    = o_Wc + (size_t)1536 * KP_CH * 2;
    const size_t o_Whn    = o_Whc + (size_t)1536 * MEM * 2;
    const size_t o_states = o_Whn + (size_t)1536 * MEM * 2;
    const size_t o_T2     = o_states + (size_t)32768 * MEM * 2;
    const size_t o_h1b    = o_T2 + (size_t)LEAVES * T2W * 2;
    const size_t o_h2b    = o_h1b + (size_t)8192 * MEM * 2;
    const size_t o_rootf  = o_h2b + (size_t)8192 * MEM * 2;
    const size_t o_h1f    = o_rootf + 2048;
    const size_t o_h2f    = o_h1f + (size_t)8192 * MEM * 4;
    const size_t NEED0    = o_h2f + (size_t)8192 * MEM * 4;

    bool tier0 = (ws_size >= NEED0);

    int*            flag   = (int*)(ws + o_flag);
    float*          biasf  = (float*)(ws + o_bias);
    unsigned short* Wl     = (unsigned short*)(ws + o_Wl);
    unsigned short* Wc     = (unsigned short*)(ws + o_Wc);
    unsigned short* Whc    = (unsigned short*)(ws + o_Whc);
    unsigned short* Whn    = (unsigned short*)(ws + o_Whn);
    unsigned short* states = (unsigned short*)(ws + o_states);
    unsigned short* T2     = (unsigned short*)(ws + o_T2);
    unsigned short* h1b    = (unsigned short*)(ws + o_h1b);
    unsigned short* h2b    = (unsigned short*)(ws + o_h2b);
    float*          rootf  = (float*)(ws + o_rootf);
    float*          h1f    = tier0 ? (float*)(ws + o_h1f) : nullptr;
    float*          h2f    = tier0 ? (float*)(ws + o_h2f) : nullptr;
    unsigned short* Xleaf  = (unsigned short*)(ws + o_T2);  // overlay, dead before T2 use

    init_flag_kernel<<<1, 64, 0, stream>>>(flag);
    detect_kernel<<<2048, 256, 0, stream>>>((const unsigned short*)embs,
                                            (const unsigned short*)ch_Wi, flag);
    convert_kernel<<<2048, 256, 0, stream>>>(flag, leaf_Wi, ch_Wi, ch_Wh, node_Wh,
                                             leaf_bi, leaf_bh, ch_bi, ch_bh,
                                             node_bi, node_bh,
                                             Wl, Wc, Whc, Whn, biasf);
    pack_xleaf_kernel<<<2048, 256, 0, stream>>>(flag, embs, tags, Xleaf);

    {
        dim3 g(LEAVES / 128, 32);
        big_gemm<0><<<g, 256, 0, stream>>>(states, T2, Xleaf, Wl, Wc, Whc, Whn,
                                           h1b, h1f, h2b, h2f, biasf, LEAVES,
                                           states + (size_t)(LEAVES - 1) * MEM, nullptr);
    }

    for (int lvl = TREE_DEPTH - 1; lvl >= 0; lvl--) {
        int n = 1 << lvl;
        int total = 2 * n * T2W;
        int blocks = (total + 255) / 256;
        if (blocks > 2048) blocks = 2048;
        pack_t2_kernel<<<blocks, 256, 0, stream>>>(flag, tags, T2, n);

        if (n >= 128) {
            dim3 g(n / 128, 32);
            big_gemm<1><<<g, 256, 0, stream>>>(states, T2, Xleaf, Wl, Wc, Whc, Whn,
                                               h1b, h1f, h2b, h2f, biasf, n, h1b, h1f);
            big_gemm<2><<<g, 256, 0, stream>>>(states, T2, Xleaf, Wl, Wc, Whc, Whn,
                                               h1b, h1f, h2b, h2f, biasf, n, h2b, h2f);
            big_gemm<3><<<g, 256, 0, stream>>>(states, T2, Xleaf, Wl, Wc, Whc, Whn,
                                               h1b, h1f, h2b, h2f, biasf, n,
                                               states + (size_t)(n - 1) * MEM, nullptr);
        } else {
            dim3 g((n + 63) / 64, 8);
            gemm_stage1<<<g, 256, 0, stream>>>(states, T2, Wc, biasf, n, h1b, h1f);
            gemm_stage2<<<g, 256, 0, stream>>>(states, T2, Wc, h1b, h1f, Whc, biasf,
                                               n, h2b, h2f);
            gemm_stage3<<<g, 256, 0, stream>>>(h2b, h2f, Whn, biasf, n,
                                               states + (size_t)(n - 1) * MEM,
                                               (n == 1) ? rootf : nullptr);
        }
    }

    copy_out_kernel<<<1, 512, 0, stream>>>(flag, states, rootf, d_out);
}

// Round 5
// 1074.651 us; speedup vs baseline: 1.3984x; 1.1518x over previous
//
#include <hip/hip_runtime.h>
#include <stdint.h>

#define MEM 512
#define TAGD 100
#define WORD 300
#define TREE_DEPTH 14
#define LEAVES 16384
#define KLEAF 400
#define KP_LEAF 416
#define KCH 712
#define KP_CH 736
#define T2W 224   // tag_child(100) | tag_parent(100) | pad(24)
#define LP 136    // LDS pitch (elems) = 17 granules -> uniform bank groups

typedef __attribute__((ext_vector_type(8))) short short8;
typedef __attribute__((ext_vector_type(4))) float floatx4;

__device__ __forceinline__ float b2f(unsigned short u) {
    union { unsigned int i; float f; } v; v.i = ((unsigned int)u) << 16; return v.f;
}
__device__ __forceinline__ unsigned short f2b(float f) {
    union { float f; unsigned int i; } v; v.f = f;
    unsigned int r = v.i + 0x7FFFu + ((v.i >> 16) & 1u);
    return (unsigned short)(r >> 16);
}
__device__ __forceinline__ float sigm(float x) { return 1.0f / (1.0f + __expf(-x)); }
__device__ __forceinline__ float tanh_f(float x) { return 1.0f - 2.0f / (__expf(2.0f * x) + 1.0f); }

// ---------------- dtype detection (inputs may be fp32 or bf16) ----------------

__global__ void init_flag_kernel(int* flag) {
    if (blockIdx.x == 0 && threadIdx.x == 0) *flag = 0;
}

__global__ void detect_kernel(const unsigned short* __restrict__ embs_u,
                              const unsigned short* __restrict__ chwi_u,
                              int* __restrict__ flag) {
    int tid = blockIdx.x * blockDim.x + threadIdx.x;
    int nth = gridDim.x * blockDim.x;
    int found = 0;
    for (int i = tid; i < LEAVES * WORD; i += nth) {
        if (((embs_u[i] >> 7) & 0xFF) == 0xFF) { found = 1; break; }
    }
    if (!found) {
        for (int i = tid; i < 1536 * KCH; i += nth) {
            if (((chwi_u[i] >> 7) & 0xFF) == 0xFF) { found = 1; break; }
        }
    }
    if (found) atomicOr(flag, 1);
}

__device__ __forceinline__ unsigned short ld_bf(int f, const void* p, int i) {
    return f ? f2b(((const float*)p)[i]) : ((const unsigned short*)p)[i];
}
__device__ __forceinline__ float ld_f32(int f, const void* p, int i) {
    return f ? ((const float*)p)[i] : b2f(((const unsigned short*)p)[i]);
}

// ---------------- conversion / packing ----------------

__global__ void convert_kernel(const int* __restrict__ flag,
                               const void* leaf_Wi, const void* ch_Wi,
                               const void* ch_Wh, const void* node_Wh,
                               const void* lbi, const void* lbh,
                               const void* cbi, const void* cbh,
                               const void* nbi, const void* nbh,
                               unsigned short* __restrict__ Wl,
                               unsigned short* __restrict__ Wc,
                               unsigned short* __restrict__ Whc,
                               unsigned short* __restrict__ Whn,
                               float* __restrict__ biasf) {
    int f = *flag;
    int tid = blockIdx.x * blockDim.x + threadIdx.x;
    int nth = gridDim.x * blockDim.x;
    for (int idx = tid; idx < 1536 * KP_LEAF; idx += nth) {
        int r = idx / KP_LEAF, c = idx % KP_LEAF;
        Wl[idx] = (c < KLEAF) ? ld_bf(f, leaf_Wi, r * KLEAF + c) : (unsigned short)0;
    }
    for (int idx = tid; idx < 1536 * KP_CH; idx += nth) {
        int r = idx / KP_CH, c = idx % KP_CH;
        Wc[idx] = (c < KCH) ? ld_bf(f, ch_Wi, r * KCH + c) : (unsigned short)0;
    }
    for (int idx = tid; idx < 1536 * MEM; idx += nth) Whc[idx] = ld_bf(f, ch_Wh, idx);
    for (int idx = tid; idx < 1536 * MEM; idx += nth) Whn[idx] = ld_bf(f, node_Wh, idx);
    for (int i = tid; i < 1536; i += nth) {
        biasf[i]            = ld_f32(f, lbi, i);
        biasf[1536 + i]     = ld_f32(f, lbh, i);
        biasf[2 * 1536 + i] = ld_f32(f, cbi, i);
        biasf[3 * 1536 + i] = ld_f32(f, cbh, i);
        biasf[4 * 1536 + i] = ld_f32(f, nbi, i);
        biasf[5 * 1536 + i] = ld_f32(f, nbh, i);
    }
}

__global__ void pack_xleaf_kernel(const int* __restrict__ flag,
                                  const void* embs, const void* tags,
                                  unsigned short* __restrict__ X) {
    int f = *flag;
    int tid = blockIdx.x * blockDim.x + threadIdx.x;
    int nth = gridDim.x * blockDim.x;
    for (int idx = tid; idx < LEAVES * KP_LEAF; idx += nth) {
        int i = idx / KP_LEAF, c = idx % KP_LEAF;
        unsigned short v;
        if (c < WORD) v = ld_bf(f, embs, i * WORD + c);
        else if (c < WORD + TAGD) v = ld_bf(f, tags, (LEAVES - 1 + i) * TAGD + (c - WORD));
        else v = 0;
        X[idx] = v;
    }
}

// All levels' T2 at once. Level lvl (n=2^lvl) occupies rows
// [32768-4n, 32768-4n+2n): first n rows = left children, next n = right.
__global__ void pack_t2_all_kernel(const int* __restrict__ flag,
                                   const void* tags,
                                   unsigned short* __restrict__ T2) {
    int f = *flag;
    int tid = blockIdx.x * blockDim.x + threadIdx.x;
    int nth = gridDim.x * blockDim.x;
    const int total = 32766 * T2W;
    for (int idx = tid; idx < total; idx += nth) {
        int r = idx / T2W, c = idx % T2W;
        int d = 32768 - r;                 // in [3, 32768]
        int lvl = 30 - __clz(d - 1);       // 13..0
        int n = 1 << lvl;
        int i = r - (32768 - 4 * n);       // [0, 2n)
        int half = (i >= n) ? 1 : 0;
        int ii = half ? (i - n) : i;
        int p = (n - 1) + ii;
        int child = 2 * p + 1 + half;
        unsigned short v;
        if (c < TAGD) v = ld_bf(f, tags, child * TAGD + c);
        else if (c < 2 * TAGD) v = ld_bf(f, tags, p * TAGD + (c - TAGD));
        else v = 0;
        T2[idx] = v;
    }
}

// ================= BIG-LEVEL GEMM ENGINE v2 =================
// Block: 256 thr = 4 waves; wave owns 16*SUBT rows; tile = 64*SUBT rows x 16 j.
// W j-slice (48 rows) double-buffered in LDS, chunks of <=128 K, pitch 136.
// A prefetched to regs before the barrier. stage2 shares r/z accumulators
// between gi and gh phases (4 slots).

struct Chunk {
    const unsigned short* A; int astride; int alpha; int beta;
    const unsigned short* W; int wstride; int wkb; int len;
};

template<int MODE, int SUBT>
__launch_bounds__(256, 2)
__global__ void big2(const unsigned short* __restrict__ states,
                     const unsigned short* __restrict__ T2l,
                     const unsigned short* __restrict__ Xleaf,
                     const unsigned short* __restrict__ Wl,
                     const unsigned short* __restrict__ Wc,
                     const unsigned short* __restrict__ Whc,
                     const unsigned short* __restrict__ Whn,
                     const unsigned short* __restrict__ h1b,
                     const float* __restrict__ h1f,
                     const unsigned short* __restrict__ h2b,
                     const float* __restrict__ h2f,
                     const float* __restrict__ biasf,
                     int n,
                     unsigned short* __restrict__ outb,
                     float* __restrict__ outf) {
    constexpr int NCH = (MODE == 0) ? 4 : (MODE == 1) ? 6 : (MODE == 2) ? 10 : 4;
    constexpr int NS  = (MODE == 2) ? 4 : 3;

    int tid = threadIdx.x;
    int w = tid >> 6, lane = tid & 63, l15 = lane & 15, quad = lane >> 4;
    int m_blk = blockIdx.x * (64 * SUBT);
    int jb = blockIdx.y * 16;
    int mw = m_blk + w * 16 * SUBT;

    __shared__ unsigned short lds[2][48 * LP];

    const unsigned short* T2r = T2l + (size_t)n * T2W;

    auto getch = [&](int c) -> Chunk {
        if (MODE == 0) {
            int kb = c * 128;
            return Chunk{Xleaf + kb, KP_LEAF, 1, 0, Wl, KP_LEAF, kb, (c < 3) ? 128 : 32};
        } else if (MODE == 1) {
            if (c < 4) return Chunk{states + c * 128, MEM, 2, 2 * n - 1, Wc, KP_CH, c * 128, 128};
            if (c == 4) return Chunk{T2l, T2W, 1, 0, Wc, KP_CH, 512, 128};
            return Chunk{T2l + 128, T2W, 1, 0, Wc, KP_CH, 640, 96};
        } else if (MODE == 2) {
            if (c < 4) return Chunk{states + c * 128, MEM, 2, 2 * n, Wc, KP_CH, c * 128, 128};
            if (c == 4) return Chunk{T2r, T2W, 1, 0, Wc, KP_CH, 512, 128};
            if (c == 5) return Chunk{T2r + 128, T2W, 1, 0, Wc, KP_CH, 640, 96};
            int kb = (c - 6) * 128;
            return Chunk{h1b + kb, MEM, 1, 0, Whc, MEM, kb, 128};
        } else {
            int kb = c * 128;
            return Chunk{h2b + kb, MEM, 1, 0, Whn, MEM, kb, 128};
        }
    };

    auto stage = [&](Chunk k, int buf) {
        int gr = k.len >> 3;   // granules (8 elems) per row
        int kc = tid & 15;
#pragma unroll
        for (int p = 0; p < 3; p++) {
            int row = (tid >> 4) + p * 16;
            if (kc < gr) {
                int gate = row >> 4, jj = row & 15;
                short8 v = *(const short8*)(k.W + (size_t)(gate * 512 + jb + jj) * k.wstride + k.wkb + kc * 8);
                *(short8*)(&lds[buf][row * LP + kc * 8]) = v;
            }
        }
    };

    floatx4 acc[SUBT][NS];
#pragma unroll
    for (int s = 0; s < SUBT; s++)
#pragma unroll
        for (int g = 0; g < NS; g++) acc[s][g] = (floatx4){0.f, 0.f, 0.f, 0.f};

    stage(getch(0), 0);

#pragma unroll
    for (int c = 0; c < NCH; c++) {
        Chunk k = getch(c);
        // A prefetch for this chunk (no LDS dependency -> overlaps barrier)
        short8 areg[4][SUBT];
#pragma unroll
        for (int ki = 0; ki < 4; ki++) {
            if (ki * 32 < k.len) {
#pragma unroll
                for (int s = 0; s < SUBT; s++) {
                    areg[ki][s] = *(const short8*)(k.A +
                        (size_t)(k.alpha * (mw + s * 16 + l15) + k.beta) * k.astride +
                        quad * 8 + ki * 32);
                }
            }
        }
        __syncthreads();
        if (c + 1 < NCH) stage(getch(c + 1), (c + 1) & 1);
        const unsigned short* lb = &lds[c & 1][l15 * LP + quad * 8];
#pragma unroll
        for (int ki = 0; ki < 4; ki++) {
            if (ki * 32 < k.len) {
                short8 b0 = *(const short8*)(lb + ki * 32);
                short8 b1 = *(const short8*)(lb + 16 * LP + ki * 32);
                short8 b2 = *(const short8*)(lb + 32 * LP + ki * 32);
#pragma unroll
                for (int s = 0; s < SUBT; s++)
                    acc[s][0] = __builtin_amdgcn_mfma_f32_16x16x32_bf16(areg[ki][s], b0, acc[s][0], 0, 0, 0);
#pragma unroll
                for (int s = 0; s < SUBT; s++)
                    acc[s][1] = __builtin_amdgcn_mfma_f32_16x16x32_bf16(areg[ki][s], b1, acc[s][1], 0, 0, 0);
                if (MODE == 2 && c >= 6) {
#pragma unroll
                    for (int s = 0; s < SUBT; s++)
                        acc[s][3] = __builtin_amdgcn_mfma_f32_16x16x32_bf16(areg[ki][s], b2, acc[s][3], 0, 0, 0);
                } else {
#pragma unroll
                    for (int s = 0; s < SUBT; s++)
                        acc[s][2] = __builtin_amdgcn_mfma_f32_16x16x32_bf16(areg[ki][s], b2, acc[s][2], 0, 0, 0);
                }
            }
        }
    }

    int j = jb + l15;
    if (MODE == 0 || MODE == 1) {
        int bo = (MODE == 0) ? 0 : 3072;
        float bir = biasf[bo + j], biz = biasf[bo + 512 + j], bin = biasf[bo + 1024 + j];
        float bhr = biasf[bo + 1536 + j], bhz = biasf[bo + 2048 + j], bhn = biasf[bo + 2560 + j];
#pragma unroll
        for (int s = 0; s < SUBT; s++)
#pragma unroll
            for (int r = 0; r < 4; r++) {
                int m = mw + s * 16 + quad * 4 + r;
                float rr = sigm(acc[s][0][r] + bir + bhr);
                float zz = sigm(acc[s][1][r] + biz + bhz);
                float nn = tanh_f(acc[s][2][r] + bin + rr * bhn);
                float h = (1.0f - zz) * nn;
                outb[(size_t)m * MEM + j] = f2b(h);
                if (MODE == 1 && outf) outf[(size_t)m * MEM + j] = h;
            }
    } else if (MODE == 2) {
        float bir = biasf[3072 + j], biz = biasf[3584 + j], bin = biasf[4096 + j];
        float bhr = biasf[4608 + j], bhz = biasf[5120 + j], bhn = biasf[5632 + j];
#pragma unroll
        for (int s = 0; s < SUBT; s++)
#pragma unroll
            for (int r = 0; r < 4; r++) {
                int m = mw + s * 16 + quad * 4 + r;
                float hp = h1f ? h1f[(size_t)m * MEM + j] : b2f(h1b[(size_t)m * MEM + j]);
                float rr = sigm(acc[s][0][r] + bir + bhr);
                float zz = sigm(acc[s][1][r] + biz + bhz);
                float nn = tanh_f(acc[s][2][r] + bin + rr * (acc[s][3][r] + bhn));
                float h = (1.0f - zz) * nn + zz * hp;
                outb[(size_t)m * MEM + j] = f2b(h);
                if (outf) outf[(size_t)m * MEM + j] = h;
            }
    } else {
        float gir = biasf[6144 + j], giz = biasf[6656 + j], gin = biasf[7168 + j];
        float bhr = biasf[7680 + j], bhz = biasf[8192 + j], bhn = biasf[8704 + j];
#pragma unroll
        for (int s = 0; s < SUBT; s++)
#pragma unroll
            for (int r = 0; r < 4; r++) {
                int m = mw + s * 16 + quad * 4 + r;
                float hp = h2f ? h2f[(size_t)m * MEM + j] : b2f(h2b[(size_t)m * MEM + j]);
                float rr = sigm(gir + acc[s][0][r] + bhr);
                float zz = sigm(giz + acc[s][1][r] + bhz);
                float nn = tanh_f(gin + rr * (acc[s][2][r] + bhn));
                float h = (1.0f - zz) * nn + zz * hp;
                outb[(size_t)m * MEM + j] = f2b(h);
            }
    }
}

// ================= SMALL-LEVEL KERNELS (proven) =================

__launch_bounds__(256)
__global__ void gemm_stage1(const unsigned short* __restrict__ states,
                            const unsigned short* __restrict__ T2,
                            const unsigned short* __restrict__ Wi,
                            const float* __restrict__ biasf,
                            int n,
                            unsigned short* __restrict__ h1b,
                            float* __restrict__ h1f) {
    int wv = threadIdx.x >> 6, lane = threadIdx.x & 63;
    int l15 = lane & 15, quad = lane >> 4, koff = quad * 8;
    int m_blk = blockIdx.x * 64;
    int jb = blockIdx.y * 64 + wv * 16;

    floatx4 acc[4][3];
#pragma unroll
    for (int s = 0; s < 4; s++)
#pragma unroll
        for (int g = 0; g < 3; g++) acc[s][g] = (floatx4){0.f, 0.f, 0.f, 0.f};
    short8 z8 = {0, 0, 0, 0, 0, 0, 0, 0};

    for (int kb = 0; kb < KP_CH; kb += 32) {
        int k0 = kb + koff;
        short8 a[4];
#pragma unroll
        for (int s = 0; s < 4; s++) {
            int row = m_blk + s * 16 + l15;
            if (row >= n) a[s] = z8;
            else if (kb < 512)
                a[s] = *(const short8*)(states + (size_t)(2 * n - 1 + 2 * row) * MEM + k0);
            else
                a[s] = *(const short8*)(T2 + (size_t)row * T2W + (k0 - 512));
        }
        short8 b[3];
#pragma unroll
        for (int g = 0; g < 3; g++)
            b[g] = *(const short8*)(Wi + (size_t)(jb + l15 + g * 512) * KP_CH + k0);
#pragma unroll
        for (int s = 0; s < 4; s++)
#pragma unroll
            for (int g = 0; g < 3; g++)
                acc[s][g] = __builtin_amdgcn_mfma_f32_16x16x32_bf16(a[s], b[g], acc[s][g], 0, 0, 0);
    }

    int j = jb + l15;
    float bir = biasf[3072 + j], biz = biasf[3584 + j], bin = biasf[4096 + j];
    float bhr = biasf[4608 + j], bhz = biasf[5120 + j], bhn = biasf[5632 + j];
#pragma unroll
    for (int s = 0; s < 4; s++)
#pragma unroll
        for (int r = 0; r < 4; r++) {
            int m = m_blk + s * 16 + quad * 4 + r;
            if (m >= n) continue;
            float rr = sigm(acc[s][0][r] + bir + bhr);
            float zz = sigm(acc[s][1][r] + biz + bhz);
            float nn = tanh_f(acc[s][2][r] + bin + rr * bhn);
            float h = (1.0f - zz) * nn;
            h1b[(size_t)m * MEM + j] = f2b(h);
            if (h1f) h1f[(size_t)m * MEM + j] = h;
        }
}

__launch_bounds__(256)
__global__ void gemm_stage2(const unsigned short* __restrict__ states,
                            const unsigned short* __restrict__ T2,
                            const unsigned short* __restrict__ Wi,
                            const unsigned short* __restrict__ h1b,
                            const float* __restrict__ h1f,
                            const unsigned short* __restrict__ Wh,
                            const float* __restrict__ biasf,
                            int n,
                            unsigned short* __restrict__ h2b,
                            float* __restrict__ h2f) {
    int wv = threadIdx.x >> 6, lane = threadIdx.x & 63;
    int l15 = lane & 15, quad = lane >> 4, koff = quad * 8;
    int m_blk = blockIdx.x * 64;
    int jb = blockIdx.y * 64 + wv * 16;

    floatx4 gi[4][3], gh[4][3];
#pragma unroll
    for (int s = 0; s < 4; s++)
#pragma unroll
        for (int g = 0; g < 3; g++) {
            gi[s][g] = (floatx4){0.f, 0.f, 0.f, 0.f};
            gh[s][g] = (floatx4){0.f, 0.f, 0.f, 0.f};
        }
    short8 z8 = {0, 0, 0, 0, 0, 0, 0, 0};

    for (int kb = 0; kb < KP_CH; kb += 32) {
        int k0 = kb + koff;
        short8 a[4];
#pragma unroll
        for (int s = 0; s < 4; s++) {
            int row = m_blk + s * 16 + l15;
            if (row >= n) a[s] = z8;
            else if (kb < 512)
                a[s] = *(const short8*)(states + (size_t)(2 * n + 2 * row) * MEM + k0);
            else
                a[s] = *(const short8*)(T2 + (size_t)(n + row) * T2W + (k0 - 512));
        }
        short8 b[3];
#pragma unroll
        for (int g = 0; g < 3; g++)
            b[g] = *(const short8*)(Wi + (size_t)(jb + l15 + g * 512) * KP_CH + k0);
#pragma unroll
        for (int s = 0; s < 4; s++)
#pragma unroll
            for (int g = 0; g < 3; g++)
                gi[s][g] = __builtin_amdgcn_mfma_f32_16x16x32_bf16(a[s], b[g], gi[s][g], 0, 0, 0);
    }

    for (int kb = 0; kb < MEM; kb += 32) {
        int k0 = kb + koff;
        short8 a[4];
#pragma unroll
        for (int s = 0; s < 4; s++) {
            int row = m_blk + s * 16 + l15;
            a[s] = (row < n) ? *(const short8*)(h1b + (size_t)row * MEM + k0) : z8;
        }
        short8 b[3];
#pragma unroll
        for (int g = 0; g < 3; g++)
            b[g] = *(const short8*)(Wh + (size_t)(jb + l15 + g * 512) * MEM + k0);
#pragma unroll
        for (int s = 0; s < 4; s++)
#pragma unroll
            for (int g = 0; g < 3; g++)
                gh[s][g] = __builtin_amdgcn_mfma_f32_16x16x32_bf16(a[s], b[g], gh[s][g], 0, 0, 0);
    }

    int j = jb + l15;
    float bir = biasf[3072 + j], biz = biasf[3584 + j], bin = biasf[4096 + j];
    float bhr = biasf[4608 + j], bhz = biasf[5120 + j], bhn = biasf[5632 + j];
#pragma unroll
    for (int s = 0; s < 4; s++)
#pragma unroll
        for (int r = 0; r < 4; r++) {
            int m = m_blk + s * 16 + quad * 4 + r;
            if (m >= n) continue;
            float hp = h1f ? h1f[(size_t)m * MEM + j] : b2f(h1b[(size_t)m * MEM + j]);
            float rr = sigm(gi[s][0][r] + bir + gh[s][0][r] + bhr);
            float zz = sigm(gi[s][1][r] + biz + gh[s][1][r] + bhz);
            float nn = tanh_f(gi[s][2][r] + bin + rr * (gh[s][2][r] + bhn));
            float h = (1.0f - zz) * nn + zz * hp;
            h2b[(size_t)m * MEM + j] = f2b(h);
            if (h2f) h2f[(size_t)m * MEM + j] = h;
        }
}

__launch_bounds__(256)
__global__ void gemm_stage3(const unsigned short* __restrict__ h2b,
                            const float* __restrict__ h2f,
                            const unsigned short* __restrict__ Wh,
                            const float* __restrict__ biasf,
                            int n,
                            unsigned short* __restrict__ out,
                            float* __restrict__ outf) {
    int wv = threadIdx.x >> 6, lane = threadIdx.x & 63;
    int l15 = lane & 15, quad = lane >> 4, koff = quad * 8;
    int m_blk = blockIdx.x * 64;
    int jb = blockIdx.y * 64 + wv * 16;

    floatx4 acc[4][3];
#pragma unroll
    for (int s = 0; s < 4; s++)
#pragma unroll
        for (int g = 0; g < 3; g++) acc[s][g] = (floatx4){0.f, 0.f, 0.f, 0.f};
    short8 z8 = {0, 0, 0, 0, 0, 0, 0, 0};

    for (int kb = 0; kb < MEM; kb += 32) {
        int k0 = kb + koff;
        short8 a[4];
#pragma unroll
        for (int s = 0; s < 4; s++) {
            int row = m_blk + s * 16 + l15;
            a[s] = (row < n) ? *(const short8*)(h2b + (size_t)row * MEM + k0) : z8;
        }
        short8 b[3];
#pragma unroll
        for (int g = 0; g < 3; g++)
            b[g] = *(const short8*)(Wh + (size_t)(jb + l15 + g * 512) * MEM + k0);
#pragma unroll
        for (int s = 0; s < 4; s++)
#pragma unroll
            for (int g = 0; g < 3; g++)
                acc[s][g] = __builtin_amdgcn_mfma_f32_16x16x32_bf16(a[s], b[g], acc[s][g], 0, 0, 0);
    }

    int j = jb + l15;
    float gir = biasf[6144 + j], giz = biasf[6656 + j], gin = biasf[7168 + j];
    float bhr = biasf[7680 + j], bhz = biasf[8192 + j], bhn = biasf[8704 + j];
#pragma unroll
    for (int s = 0; s < 4; s++)
#pragma unroll
        for (int r = 0; r < 4; r++) {
            int m = m_blk + s * 16 + quad * 4 + r;
            if (m >= n) continue;
            float hp = h2f ? h2f[(size_t)m * MEM + j] : b2f(h2b[(size_t)m * MEM + j]);
            float rr = sigm(gir + acc[s][0][r] + bhr);
            float zz = sigm(giz + acc[s][1][r] + bhz);
            float nn = tanh_f(gin + rr * (acc[s][2][r] + bhn));
            float h = (1.0f - zz) * nn + zz * hp;
            out[(size_t)m * MEM + j] = f2b(h);
            if (outf) outf[(size_t)m * MEM + j] = h;
        }
}

__global__ void copy_out_kernel(const int* __restrict__ flag,
                                const unsigned short* __restrict__ states,
                                const float* __restrict__ rootf,
                                void* __restrict__ out) {
    int j = threadIdx.x;
    if (j >= MEM) return;
    if (*flag) ((float*)out)[j] = rootf[j];
    else ((unsigned short*)out)[j] = states[j];
}

// ---------------- launch ----------------

extern "C" void kernel_launch(void* const* d_in, const int* in_sizes, int n_in,
                              void* d_out, int out_size, void* d_ws, size_t ws_size,
                              hipStream_t stream) {
    const void* embs    = d_in[0];
    const void* tags    = d_in[1];
    const void* leaf_Wi = d_in[2];
    const void* leaf_bi = d_in[4];
    const void* leaf_bh = d_in[5];
    const void* node_Wh = d_in[7];
    const void* node_bi = d_in[8];
    const void* node_bh = d_in[9];
    const void* ch_Wi   = d_in[10];
    const void* ch_Wh   = d_in[11];
    const void* ch_bi   = d_in[12];
    const void* ch_bh   = d_in[13];
    (void)in_sizes; (void)n_in; (void)out_size;

    char* ws = (char*)d_ws;
    const size_t o_flag   = 0;
    const size_t o_bias   = 256;
    const size_t o_Wl     = o_bias + 36864;
    const size_t o_Wc     = o_Wl + (size_t)1536 * KP_LEAF * 2;
    const size_t o_Whc    = o_Wc + (size_t)1536 * KP_CH * 2;
    const size_t o_Whn    = o_Whc + (size_t)1536 * MEM * 2;
    const size_t o_states = o_Whn + (size_t)1536 * MEM * 2;
    const size_t o_T2     = o_states + (size_t)32768 * MEM * 2;
    const size_t o_h1b    = o_T2 + (size_t)32768 * T2W * 2;
    const size_t o_h2b    = o_h1b + (size_t)8192 * MEM * 2;
    const size_t o_rootf  = o_h2b + (size_t)8192 * MEM * 2;
    const size_t o_h1f    = o_rootf + 2048;
    const size_t o_h2f    = o_h1f + (size_t)8192 * MEM * 4;
    const size_t NEED0    = o_h2f + (size_t)8192 * MEM * 4;   // ~105 MB

    bool tier0 = (ws_size >= NEED0);

    int*            flag   = (int*)(ws + o_flag);
    float*          biasf  = (float*)(ws + o_bias);
    unsigned short* Wl     = (unsigned short*)(ws + o_Wl);
    unsigned short* Wc     = (unsigned short*)(ws + o_Wc);
    unsigned short* Whc    = (unsigned short*)(ws + o_Whc);
    unsigned short* Whn    = (unsigned short*)(ws + o_Whn);
    unsigned short* states = (unsigned short*)(ws + o_states);
    unsigned short* T2all  = (unsigned short*)(ws + o_T2);
    unsigned short* h1b    = (unsigned short*)(ws + o_h1b);
    unsigned short* h2b    = (unsigned short*)(ws + o_h2b);
    float*          rootf  = (float*)(ws + o_rootf);
    float*          h1f    = tier0 ? (float*)(ws + o_h1f) : nullptr;
    float*          h2f    = tier0 ? (float*)(ws + o_h2f) : nullptr;
    // Xleaf (13.63 MB) overlays h1b+h2b (16.78 MB): dead before lvl-13 stage1
    unsigned short* Xleaf  = (unsigned short*)(ws + o_h1b);

    init_flag_kernel<<<1, 64, 0, stream>>>(flag);
    detect_kernel<<<2048, 256, 0, stream>>>((const unsigned short*)embs,
                                            (const unsigned short*)ch_Wi, flag);
    convert_kernel<<<2048, 256, 0, stream>>>(flag, leaf_Wi, ch_Wi, ch_Wh, node_Wh,
                                             leaf_bi, leaf_bh, ch_bi, ch_bh,
                                             node_bi, node_bh,
                                             Wl, Wc, Whc, Whn, biasf);
    pack_t2_all_kernel<<<2048, 256, 0, stream>>>(flag, tags, T2all);
    pack_xleaf_kernel<<<2048, 256, 0, stream>>>(flag, embs, tags, Xleaf);

    big2<0, 4><<<dim3(LEAVES / 256, 32), 256, 0, stream>>>(
        states, T2all, Xleaf, Wl, Wc, Whc, Whn, h1b, h1f, h2b, h2f, biasf,
        LEAVES, states + (size_t)(LEAVES - 1) * MEM, nullptr);

#define LAUNCH_BIG(M, S, OB, OF) \
    big2<M, S><<<dim3(n / (64 * S), 32), 256, 0, stream>>>( \
        states, T2l, nullptr, Wl, Wc, Whc, Whn, h1b, h1f, h2b, h2f, biasf, n, OB, OF)

    for (int lvl = TREE_DEPTH - 1; lvl >= 0; lvl--) {
        int n = 1 << lvl;
        const unsigned short* T2l = T2all + (size_t)(32768 - 4 * n) * T2W;
        unsigned short* st_out = states + (size_t)(n - 1) * MEM;

        if (n >= 2048) {
            LAUNCH_BIG(1, 4, h1b, h1f);
            LAUNCH_BIG(2, 4, h2b, h2f);
            LAUNCH_BIG(3, 4, st_out, nullptr);
        } else if (n >= 1024) {
            LAUNCH_BIG(1, 2, h1b, h1f);
            LAUNCH_BIG(2, 2, h2b, h2f);
            LAUNCH_BIG(3, 2, st_out, nullptr);
        } else if (n >= 128) {
            LAUNCH_BIG(1, 1, h1b, h1f);
            LAUNCH_BIG(2, 1, h2b, h2f);
            LAUNCH_BIG(3, 1, st_out, nullptr);
        } else {
            dim3 g((n + 63) / 64, 8);
            gemm_stage1<<<g, 256, 0, stream>>>(states, T2l, Wc, biasf, n, h1b, h1f);
            gemm_stage2<<<g, 256, 0, stream>>>(states, T2l, Wc, h1b, h1f, Whc, biasf,
                                               n, h2b, h2f);
            gemm_stage3<<<g, 256, 0, stream>>>(h2b, h2f, Whn, biasf, n, st_out,
                                               (n == 1) ? rootf : nullptr);
        }
    }

    copy_out_kernel<<<1, 512, 0, stream>>>(flag, states, rootf, d_out);
}

// Round 6
// 1046.087 us; speedup vs baseline: 1.4365x; 1.0273x over previous
//
#include <hip/hip_runtime.h>
#include <stdint.h>

#define MEM 512
#define TAGD 100
#define WORD 300
#define TREE_DEPTH 14
#define LEAVES 16384
#define KLEAF 400
#define KP_LEAF 416
#define KCH 712
#define KP_CH 736
#define T2W 224   // tag_child(100) | tag_parent(100) | pad(24)
#define LP 136    // big2 LDS pitch
#define AP 72     // big3 A-LDS pitch (144B -> 4-bank row spread, 2-way free)

typedef __attribute__((ext_vector_type(8))) short short8;
typedef __attribute__((ext_vector_type(4))) float floatx4;

__device__ __forceinline__ float b2f(unsigned short u) {
    union { unsigned int i; float f; } v; v.i = ((unsigned int)u) << 16; return v.f;
}
__device__ __forceinline__ unsigned short f2b(float f) {
    union { float f; unsigned int i; } v; v.f = f;
    unsigned int r = v.i + 0x7FFFu + ((v.i >> 16) & 1u);
    return (unsigned short)(r >> 16);
}
__device__ __forceinline__ float sigm(float x) { return 1.0f / (1.0f + __expf(-x)); }
__device__ __forceinline__ float tanh_f(float x) { return 1.0f - 2.0f / (__expf(2.0f * x) + 1.0f); }

// ---------------- dtype detection ----------------

__global__ void init_flag_kernel(int* flag) {
    if (blockIdx.x == 0 && threadIdx.x == 0) *flag = 0;
}

__global__ void detect_kernel(const unsigned short* __restrict__ embs_u,
                              const unsigned short* __restrict__ chwi_u,
                              int* __restrict__ flag) {
    int tid = blockIdx.x * blockDim.x + threadIdx.x;
    int nth = gridDim.x * blockDim.x;
    int found = 0;
    for (int i = tid; i < LEAVES * WORD; i += nth) {
        if (((embs_u[i] >> 7) & 0xFF) == 0xFF) { found = 1; break; }
    }
    if (!found) {
        for (int i = tid; i < 1536 * KCH; i += nth) {
            if (((chwi_u[i] >> 7) & 0xFF) == 0xFF) { found = 1; break; }
        }
    }
    if (found) atomicOr(flag, 1);
}

__device__ __forceinline__ unsigned short ld_bf(int f, const void* p, int i) {
    return f ? f2b(((const float*)p)[i]) : ((const unsigned short*)p)[i];
}
__device__ __forceinline__ float ld_f32(int f, const void* p, int i) {
    return f ? ((const float*)p)[i] : b2f(((const unsigned short*)p)[i]);
}

// ---------------- conversion / packing ----------------

__global__ void convert_kernel(const int* __restrict__ flag,
                               const void* leaf_Wi, const void* ch_Wi,
                               const void* ch_Wh, const void* node_Wh,
                               const void* lbi, const void* lbh,
                               const void* cbi, const void* cbh,
                               const void* nbi, const void* nbh,
                               unsigned short* __restrict__ Wl,
                               unsigned short* __restrict__ Wc,
                               unsigned short* __restrict__ Whc,
                               unsigned short* __restrict__ Whn,
                               float* __restrict__ biasf) {
    int f = *flag;
    int tid = blockIdx.x * blockDim.x + threadIdx.x;
    int nth = gridDim.x * blockDim.x;
    for (int idx = tid; idx < 1536 * KP_LEAF; idx += nth) {
        int r = idx / KP_LEAF, c = idx % KP_LEAF;
        Wl[idx] = (c < KLEAF) ? ld_bf(f, leaf_Wi, r * KLEAF + c) : (unsigned short)0;
    }
    for (int idx = tid; idx < 1536 * KP_CH; idx += nth) {
        int r = idx / KP_CH, c = idx % KP_CH;
        Wc[idx] = (c < KCH) ? ld_bf(f, ch_Wi, r * KCH + c) : (unsigned short)0;
    }
    for (int idx = tid; idx < 1536 * MEM; idx += nth) Whc[idx] = ld_bf(f, ch_Wh, idx);
    for (int idx = tid; idx < 1536 * MEM; idx += nth) Whn[idx] = ld_bf(f, node_Wh, idx);
    for (int i = tid; i < 1536; i += nth) {
        biasf[i]            = ld_f32(f, lbi, i);
        biasf[1536 + i]     = ld_f32(f, lbh, i);
        biasf[2 * 1536 + i] = ld_f32(f, cbi, i);
        biasf[3 * 1536 + i] = ld_f32(f, cbh, i);
        biasf[4 * 1536 + i] = ld_f32(f, nbi, i);
        biasf[5 * 1536 + i] = ld_f32(f, nbh, i);
    }
}

__global__ void pack_xleaf_kernel(const int* __restrict__ flag,
                                  const void* embs, const void* tags,
                                  unsigned short* __restrict__ X) {
    int f = *flag;
    int tid = blockIdx.x * blockDim.x + threadIdx.x;
    int nth = gridDim.x * blockDim.x;
    for (int idx = tid; idx < LEAVES * KP_LEAF; idx += nth) {
        int i = idx / KP_LEAF, c = idx % KP_LEAF;
        unsigned short v;
        if (c < WORD) v = ld_bf(f, embs, i * WORD + c);
        else if (c < WORD + TAGD) v = ld_bf(f, tags, (LEAVES - 1 + i) * TAGD + (c - WORD));
        else v = 0;
        X[idx] = v;
    }
}

// All levels' T2. Level lvl (n=2^lvl): rows [32768-4n, 32768-4n+2n).
__global__ void pack_t2_all_kernel(const int* __restrict__ flag,
                                   const void* tags,
                                   unsigned short* __restrict__ T2) {
    int f = *flag;
    int tid = blockIdx.x * blockDim.x + threadIdx.x;
    int nth = gridDim.x * blockDim.x;
    const int total = 32766 * T2W;
    for (int idx = tid; idx < total; idx += nth) {
        int r = idx / T2W, c = idx % T2W;
        int d = 32768 - r;
        int lvl = 30 - __clz(d - 1);
        int n = 1 << lvl;
        int i = r - (32768 - 4 * n);
        int half = (i >= n) ? 1 : 0;
        int ii = half ? (i - n) : i;
        int p = (n - 1) + ii;
        int child = 2 * p + 1 + half;
        unsigned short v;
        if (c < TAGD) v = ld_bf(f, tags, child * TAGD + c);
        else if (c < 2 * TAGD) v = ld_bf(f, tags, p * TAGD + (c - TAGD));
        else v = 0;
        T2[idx] = v;
    }
}

struct Chunk {
    const unsigned short* A; int astride; int alpha; int beta;
    const unsigned short* W; int wstride; int wkb; int len;
};

// ================= BIG3: wide-j traffic-optimized engine (M multiple of 128) ==========
// 512 thr / 8 waves. Tile 128m x (64j x 3 gates). Wave (wm,wj): 64m x 16j.
// A gathered->LDS (pitch 72, dbuf, K<=64 chunks), shared across j-waves.
// W read per-wave direct from global; flat grid with jblk = bid&7 -> per-XCD
// W-slice (283KB) stays L2-resident. stage2 shares r/z accumulators.

template<int MODE>
__launch_bounds__(512, 3)
__global__ void big3(const unsigned short* __restrict__ states,
                     const unsigned short* __restrict__ T2l,
                     const unsigned short* __restrict__ Xleaf,
                     const unsigned short* __restrict__ Wl,
                     const unsigned short* __restrict__ Wc,
                     const unsigned short* __restrict__ Whc,
                     const unsigned short* __restrict__ Whn,
                     const unsigned short* __restrict__ h1b,
                     const float* __restrict__ h1f,
                     const unsigned short* __restrict__ h2b,
                     const float* __restrict__ h2f,
                     const float* __restrict__ biasf,
                     int n,
                     unsigned short* __restrict__ outb,
                     float* __restrict__ outf) {
    constexpr int NCH = (MODE == 0) ? 7 : (MODE == 1) ? 12 : (MODE == 2) ? 20 : 8;
    constexpr int NS  = (MODE == 2) ? 4 : 3;

    int tid = threadIdx.x;
    int w = tid >> 6, lane = tid & 63, l15 = lane & 15, quad = lane >> 4;
    int wm = w >> 2, wj = w & 3;
    int bid = blockIdx.x;
    int jblk = bid & 7, mb = bid >> 3;
    int m_blk = mb * 128;
    int jb = jblk * 64;

    __shared__ unsigned short lA[2][128 * AP];

    const unsigned short* T2r = T2l + (size_t)n * T2W;

    auto getch = [&](int c) -> Chunk {
        if (MODE == 0) {
            return Chunk{Xleaf + c * 64, KP_LEAF, 1, 0, Wl, KP_LEAF, c * 64, (c < 6) ? 64 : 32};
        } else if (MODE == 1) {
            if (c < 8) return Chunk{states + c * 64, MEM, 2, 2 * n - 1, Wc, KP_CH, c * 64, 64};
            int kb = (c - 8) * 64;
            return Chunk{T2l + kb, T2W, 1, 0, Wc, KP_CH, 512 + kb, (c < 11) ? 64 : 32};
        } else if (MODE == 2) {
            if (c < 8) return Chunk{states + c * 64, MEM, 2, 2 * n, Wc, KP_CH, c * 64, 64};
            if (c < 12) {
                int kb = (c - 8) * 64;
                return Chunk{T2r + kb, T2W, 1, 0, Wc, KP_CH, 512 + kb, (c < 11) ? 64 : 32};
            }
            int kb = (c - 12) * 64;
            return Chunk{h1b + kb, MEM, 1, 0, Whc, MEM, kb, 64};
        } else {
            return Chunk{h2b + c * 64, MEM, 1, 0, Whn, MEM, c * 64, 64};
        }
    };

    auto stageA = [&](Chunk k, int buf) {
        if (k.len == 64) {
            // 128 rows x 8 granules = 1024 slots, 2 per thread
#pragma unroll
            for (int p = 0; p < 2; p++) {
                int idx = tid + p * 512;
                int row = idx >> 3, gr = idx & 7;
                short8 v = *(const short8*)(k.A +
                    (size_t)(k.alpha * (m_blk + row) + k.beta) * k.astride + gr * 8);
                *(short8*)(&lA[buf][row * AP + gr * 8]) = v;
            }
        } else {
            // len 32: 128 x 4 = 512 slots
            int row = tid >> 2, gr = tid & 3;
            short8 v = *(const short8*)(k.A +
                (size_t)(k.alpha * (m_blk + row) + k.beta) * k.astride + gr * 8);
            *(short8*)(&lA[buf][row * AP + gr * 8]) = v;
        }
    };

    floatx4 acc[4][NS];
#pragma unroll
    for (int s = 0; s < 4; s++)
#pragma unroll
        for (int g = 0; g < NS; g++) acc[s][g] = (floatx4){0.f, 0.f, 0.f, 0.f};

    stageA(getch(0), 0);

#pragma unroll
    for (int c = 0; c < NCH; c++) {
        Chunk k = getch(c);
        __syncthreads();
        if (c + 1 < NCH) stageA(getch(c + 1), (c + 1) & 1);
        // W fragments for this chunk: direct global (L2-resident slice)
        int wrow = jb + wj * 16 + l15;
        short8 wreg[2][3];
#pragma unroll
        for (int ki = 0; ki < 2; ki++) {
            if (ki * 32 < k.len) {
#pragma unroll
                for (int g = 0; g < 3; g++)
                    wreg[ki][g] = *(const short8*)(k.W +
                        (size_t)(g * 512 + wrow) * k.wstride + k.wkb + ki * 32 + quad * 8);
            }
        }
        const unsigned short* la = &lA[c & 1][(wm * 64 + l15) * AP + quad * 8];
        constexpr int NSLOT = (MODE == 2) ? 1 : 0;  // dummy to keep template happy
        (void)NSLOT;
#pragma unroll
        for (int ki = 0; ki < 2; ki++) {
            if (ki * 32 < k.len) {
                short8 a[4];
#pragma unroll
                for (int s = 0; s < 4; s++)
                    a[s] = *(const short8*)(la + s * 16 * AP + ki * 32);
#pragma unroll
                for (int s = 0; s < 4; s++)
                    acc[s][0] = __builtin_amdgcn_mfma_f32_16x16x32_bf16(a[s], wreg[ki][0], acc[s][0], 0, 0, 0);
#pragma unroll
                for (int s = 0; s < 4; s++)
                    acc[s][1] = __builtin_amdgcn_mfma_f32_16x16x32_bf16(a[s], wreg[ki][1], acc[s][1], 0, 0, 0);
                if (MODE == 2 && c >= 12) {
#pragma unroll
                    for (int s = 0; s < 4; s++)
                        acc[s][3] = __builtin_amdgcn_mfma_f32_16x16x32_bf16(a[s], wreg[ki][2], acc[s][3], 0, 0, 0);
                } else {
#pragma unroll
                    for (int s = 0; s < 4; s++)
                        acc[s][2] = __builtin_amdgcn_mfma_f32_16x16x32_bf16(a[s], wreg[ki][2], acc[s][2], 0, 0, 0);
                }
            }
        }
    }

    int j = jb + wj * 16 + l15;
    if (MODE == 0 || MODE == 1) {
        int bo = (MODE == 0) ? 0 : 3072;
        float bir = biasf[bo + j], biz = biasf[bo + 512 + j], bin = biasf[bo + 1024 + j];
        float bhr = biasf[bo + 1536 + j], bhz = biasf[bo + 2048 + j], bhn = biasf[bo + 2560 + j];
#pragma unroll
        for (int s = 0; s < 4; s++)
#pragma unroll
            for (int r = 0; r < 4; r++) {
                int m = m_blk + wm * 64 + s * 16 + quad * 4 + r;
                float rr = sigm(acc[s][0][r] + bir + bhr);
                float zz = sigm(acc[s][1][r] + biz + bhz);
                float nn = tanh_f(acc[s][2][r] + bin + rr * bhn);
                float h = (1.0f - zz) * nn;
                outb[(size_t)m * MEM + j] = f2b(h);
                if (MODE == 1 && outf) outf[(size_t)m * MEM + j] = h;
            }
    } else if (MODE == 2) {
        float bir = biasf[3072 + j], biz = biasf[3584 + j], bin = biasf[4096 + j];
        float bhr = biasf[4608 + j], bhz = biasf[5120 + j], bhn = biasf[5632 + j];
#pragma unroll
        for (int s = 0; s < 4; s++)
#pragma unroll
            for (int r = 0; r < 4; r++) {
                int m = m_blk + wm * 64 + s * 16 + quad * 4 + r;
                float hp = h1f ? h1f[(size_t)m * MEM + j] : b2f(h1b[(size_t)m * MEM + j]);
                float rr = sigm(acc[s][0][r] + bir + bhr);
                float zz = sigm(acc[s][1][r] + biz + bhz);
                float nn = tanh_f(acc[s][2][r] + bin + rr * (acc[s][3][r] + bhn));
                float h = (1.0f - zz) * nn + zz * hp;
                outb[(size_t)m * MEM + j] = f2b(h);
                if (outf) outf[(size_t)m * MEM + j] = h;
            }
    } else {
        float gir = biasf[6144 + j], giz = biasf[6656 + j], gin = biasf[7168 + j];
        float bhr = biasf[7680 + j], bhz = biasf[8192 + j], bhn = biasf[8704 + j];
#pragma unroll
        for (int s = 0; s < 4; s++)
#pragma unroll
            for (int r = 0; r < 4; r++) {
                int m = m_blk + wm * 64 + s * 16 + quad * 4 + r;
                float hp = h2f ? h2f[(size_t)m * MEM + j] : b2f(h2b[(size_t)m * MEM + j]);
                float rr = sigm(gir + acc[s][0][r] + bhr);
                float zz = sigm(giz + acc[s][1][r] + bhz);
                float nn = tanh_f(gin + rr * (acc[s][2][r] + bhn));
                float h = (1.0f - zz) * nn + zz * hp;
                outb[(size_t)m * MEM + j] = f2b(h);
            }
    }
}

// ================= BIG2 engine (mid levels 128..1024) =================

template<int MODE, int SUBT>
__launch_bounds__(256, 2)
__global__ void big2(const unsigned short* __restrict__ states,
                     const unsigned short* __restrict__ T2l,
                     const unsigned short* __restrict__ Xleaf,
                     const unsigned short* __restrict__ Wl,
                     const unsigned short* __restrict__ Wc,
                     const unsigned short* __restrict__ Whc,
                     const unsigned short* __restrict__ Whn,
                     const unsigned short* __restrict__ h1b,
                     const float* __restrict__ h1f,
                     const unsigned short* __restrict__ h2b,
                     const float* __restrict__ h2f,
                     const float* __restrict__ biasf,
                     int n,
                     unsigned short* __restrict__ outb,
                     float* __restrict__ outf) {
    constexpr int NCH = (MODE == 0) ? 4 : (MODE == 1) ? 6 : (MODE == 2) ? 10 : 4;
    constexpr int NS  = (MODE == 2) ? 4 : 3;

    int tid = threadIdx.x;
    int w = tid >> 6, lane = tid & 63, l15 = lane & 15, quad = lane >> 4;
    int m_blk = blockIdx.x * (64 * SUBT);
    int jb = blockIdx.y * 16;
    int mw = m_blk + w * 16 * SUBT;

    __shared__ unsigned short lds[2][48 * LP];

    const unsigned short* T2r = T2l + (size_t)n * T2W;

    auto getch = [&](int c) -> Chunk {
        if (MODE == 0) {
            int kb = c * 128;
            return Chunk{Xleaf + kb, KP_LEAF, 1, 0, Wl, KP_LEAF, kb, (c < 3) ? 128 : 32};
        } else if (MODE == 1) {
            if (c < 4) return Chunk{states + c * 128, MEM, 2, 2 * n - 1, Wc, KP_CH, c * 128, 128};
            if (c == 4) return Chunk{T2l, T2W, 1, 0, Wc, KP_CH, 512, 128};
            return Chunk{T2l + 128, T2W, 1, 0, Wc, KP_CH, 640, 96};
        } else if (MODE == 2) {
            if (c < 4) return Chunk{states + c * 128, MEM, 2, 2 * n, Wc, KP_CH, c * 128, 128};
            if (c == 4) return Chunk{T2r, T2W, 1, 0, Wc, KP_CH, 512, 128};
            if (c == 5) return Chunk{T2r + 128, T2W, 1, 0, Wc, KP_CH, 640, 96};
            int kb = (c - 6) * 128;
            return Chunk{h1b + kb, MEM, 1, 0, Whc, MEM, kb, 128};
        } else {
            int kb = c * 128;
            return Chunk{h2b + kb, MEM, 1, 0, Whn, MEM, kb, 128};
        }
    };

    auto stage = [&](Chunk k, int buf) {
        int gr = k.len >> 3;
        int kc = tid & 15;
#pragma unroll
        for (int p = 0; p < 3; p++) {
            int row = (tid >> 4) + p * 16;
            if (kc < gr) {
                int gate = row >> 4, jj = row & 15;
                short8 v = *(const short8*)(k.W + (size_t)(gate * 512 + jb + jj) * k.wstride + k.wkb + kc * 8);
                *(short8*)(&lds[buf][row * LP + kc * 8]) = v;
            }
        }
    };

    floatx4 acc[SUBT][NS];
#pragma unroll
    for (int s = 0; s < SUBT; s++)
#pragma unroll
        for (int g = 0; g < NS; g++) acc[s][g] = (floatx4){0.f, 0.f, 0.f, 0.f};

    stage(getch(0), 0);

#pragma unroll
    for (int c = 0; c < NCH; c++) {
        Chunk k = getch(c);
        __syncthreads();
        if (c + 1 < NCH) stage(getch(c + 1), (c + 1) & 1);
        short8 areg[4][SUBT];
#pragma unroll
        for (int ki = 0; ki < 4; ki++) {
            if (ki * 32 < k.len) {
#pragma unroll
                for (int s = 0; s < SUBT; s++) {
                    areg[ki][s] = *(const short8*)(k.A +
                        (size_t)(k.alpha * (mw + s * 16 + l15) + k.beta) * k.astride +
                        quad * 8 + ki * 32);
                }
            }
        }
        const unsigned short* lb = &lds[c & 1][l15 * LP + quad * 8];
#pragma unroll
        for (int ki = 0; ki < 4; ki++) {
            if (ki * 32 < k.len) {
                short8 b0 = *(const short8*)(lb + ki * 32);
                short8 b1 = *(const short8*)(lb + 16 * LP + ki * 32);
                short8 b2 = *(const short8*)(lb + 32 * LP + ki * 32);
#pragma unroll
                for (int s = 0; s < SUBT; s++)
                    acc[s][0] = __builtin_amdgcn_mfma_f32_16x16x32_bf16(areg[ki][s], b0, acc[s][0], 0, 0, 0);
#pragma unroll
                for (int s = 0; s < SUBT; s++)
                    acc[s][1] = __builtin_amdgcn_mfma_f32_16x16x32_bf16(areg[ki][s], b1, acc[s][1], 0, 0, 0);
                if (MODE == 2 && c >= 6) {
#pragma unroll
                    for (int s = 0; s < SUBT; s++)
                        acc[s][3] = __builtin_amdgcn_mfma_f32_16x16x32_bf16(areg[ki][s], b2, acc[s][3], 0, 0, 0);
                } else {
#pragma unroll
                    for (int s = 0; s < SUBT; s++)
                        acc[s][2] = __builtin_amdgcn_mfma_f32_16x16x32_bf16(areg[ki][s], b2, acc[s][2], 0, 0, 0);
                }
            }
        }
    }

    int j = jb + l15;
    if (MODE == 0 || MODE == 1) {
        int bo = (MODE == 0) ? 0 : 3072;
        float bir = biasf[bo + j], biz = biasf[bo + 512 + j], bin = biasf[bo + 1024 + j];
        float bhr = biasf[bo + 1536 + j], bhz = biasf[bo + 2048 + j], bhn = biasf[bo + 2560 + j];
#pragma unroll
        for (int s = 0; s < SUBT; s++)
#pragma unroll
            for (int r = 0; r < 4; r++) {
                int m = mw + s * 16 + quad * 4 + r;
                float rr = sigm(acc[s][0][r] + bir + bhr);
                float zz = sigm(acc[s][1][r] + biz + bhz);
                float nn = tanh_f(acc[s][2][r] + bin + rr * bhn);
                float h = (1.0f - zz) * nn;
                outb[(size_t)m * MEM + j] = f2b(h);
                if (MODE == 1 && outf) outf[(size_t)m * MEM + j] = h;
            }
    } else if (MODE == 2) {
        float bir = biasf[3072 + j], biz = biasf[3584 + j], bin = biasf[4096 + j];
        float bhr = biasf[4608 + j], bhz = biasf[5120 + j], bhn = biasf[5632 + j];
#pragma unroll
        for (int s = 0; s < SUBT; s++)
#pragma unroll
            for (int r = 0; r < 4; r++) {
                int m = mw + s * 16 + quad * 4 + r;
                float hp = h1f ? h1f[(size_t)m * MEM + j] : b2f(h1b[(size_t)m * MEM + j]);
                float rr = sigm(acc[s][0][r] + bir + bhr);
                float zz = sigm(acc[s][1][r] + biz + bhz);
                float nn = tanh_f(acc[s][2][r] + bin + rr * (acc[s][3][r] + bhn));
                float h = (1.0f - zz) * nn + zz * hp;
                outb[(size_t)m * MEM + j] = f2b(h);
                if (outf) outf[(size_t)m * MEM + j] = h;
            }
    } else {
        float gir = biasf[6144 + j], giz = biasf[6656 + j], gin = biasf[7168 + j];
        float bhr = biasf[7680 + j], bhz = biasf[8192 + j], bhn = biasf[8704 + j];
#pragma unroll
        for (int s = 0; s < SUBT; s++)
#pragma unroll
            for (int r = 0; r < 4; r++) {
                int m = mw + s * 16 + quad * 4 + r;
                float hp = h2f ? h2f[(size_t)m * MEM + j] : b2f(h2b[(size_t)m * MEM + j]);
                float rr = sigm(gir + acc[s][0][r] + bhr);
                float zz = sigm(giz + acc[s][1][r] + bhz);
                float nn = tanh_f(gin + rr * (acc[s][2][r] + bhn));
                float h = (1.0f - zz) * nn + zz * hp;
                outb[(size_t)m * MEM + j] = f2b(h);
            }
    }
}

// ================= SMALL-LEVEL KERNELS (proven) =================

__launch_bounds__(256)
__global__ void gemm_stage1(const unsigned short* __restrict__ states,
                            const unsigned short* __restrict__ T2,
                            const unsigned short* __restrict__ Wi,
                            const float* __restrict__ biasf,
                            int n,
                            unsigned short* __restrict__ h1b,
                            float* __restrict__ h1f) {
    int wv = threadIdx.x >> 6, lane = threadIdx.x & 63;
    int l15 = lane & 15, quad = lane >> 4, koff = quad * 8;
    int m_blk = blockIdx.x * 64;
    int jb = blockIdx.y * 64 + wv * 16;

    floatx4 acc[4][3];
#pragma unroll
    for (int s = 0; s < 4; s++)
#pragma unroll
        for (int g = 0; g < 3; g++) acc[s][g] = (floatx4){0.f, 0.f, 0.f, 0.f};
    short8 z8 = {0, 0, 0, 0, 0, 0, 0, 0};

    for (int kb = 0; kb < KP_CH; kb += 32) {
        int k0 = kb + koff;
        short8 a[4];
#pragma unroll
        for (int s = 0; s < 4; s++) {
            int row = m_blk + s * 16 + l15;
            if (row >= n) a[s] = z8;
            else if (kb < 512)
                a[s] = *(const short8*)(states + (size_t)(2 * n - 1 + 2 * row) * MEM + k0);
            else
                a[s] = *(const short8*)(T2 + (size_t)row * T2W + (k0 - 512));
        }
        short8 b[3];
#pragma unroll
        for (int g = 0; g < 3; g++)
            b[g] = *(const short8*)(Wi + (size_t)(jb + l15 + g * 512) * KP_CH + k0);
#pragma unroll
        for (int s = 0; s < 4; s++)
#pragma unroll
            for (int g = 0; g < 3; g++)
                acc[s][g] = __builtin_amdgcn_mfma_f32_16x16x32_bf16(a[s], b[g], acc[s][g], 0, 0, 0);
    }

    int j = jb + l15;
    float bir = biasf[3072 + j], biz = biasf[3584 + j], bin = biasf[4096 + j];
    float bhr = biasf[4608 + j], bhz = biasf[5120 + j], bhn = biasf[5632 + j];
#pragma unroll
    for (int s = 0; s < 4; s++)
#pragma unroll
        for (int r = 0; r < 4; r++) {
            int m = m_blk + s * 16 + quad * 4 + r;
            if (m >= n) continue;
            float rr = sigm(acc[s][0][r] + bir + bhr);
            float zz = sigm(acc[s][1][r] + biz + bhz);
            float nn = tanh_f(acc[s][2][r] + bin + rr * bhn);
            float h = (1.0f - zz) * nn;
            h1b[(size_t)m * MEM + j] = f2b(h);
            if (h1f) h1f[(size_t)m * MEM + j] = h;
        }
}

__launch_bounds__(256)
__global__ void gemm_stage2(const unsigned short* __restrict__ states,
                            const unsigned short* __restrict__ T2,
                            const unsigned short* __restrict__ Wi,
                            const unsigned short* __restrict__ h1b,
                            const float* __restrict__ h1f,
                            const unsigned short* __restrict__ Wh,
                            const float* __restrict__ biasf,
                            int n,
                            unsigned short* __restrict__ h2b,
                            float* __restrict__ h2f) {
    int wv = threadIdx.x >> 6, lane = threadIdx.x & 63;
    int l15 = lane & 15, quad = lane >> 4, koff = quad * 8;
    int m_blk = blockIdx.x * 64;
    int jb = blockIdx.y * 64 + wv * 16;

    floatx4 gi[4][3], gh[4][3];
#pragma unroll
    for (int s = 0; s < 4; s++)
#pragma unroll
        for (int g = 0; g < 3; g++) {
            gi[s][g] = (floatx4){0.f, 0.f, 0.f, 0.f};
            gh[s][g] = (floatx4){0.f, 0.f, 0.f, 0.f};
        }
    short8 z8 = {0, 0, 0, 0, 0, 0, 0, 0};

    for (int kb = 0; kb < KP_CH; kb += 32) {
        int k0 = kb + koff;
        short8 a[4];
#pragma unroll
        for (int s = 0; s < 4; s++) {
            int row = m_blk + s * 16 + l15;
            if (row >= n) a[s] = z8;
            else if (kb < 512)
                a[s] = *(const short8*)(states + (size_t)(2 * n + 2 * row) * MEM + k0);
            else
                a[s] = *(const short8*)(T2 + (size_t)(n + row) * T2W + (k0 - 512));
        }
        short8 b[3];
#pragma unroll
        for (int g = 0; g < 3; g++)
            b[g] = *(const short8*)(Wi + (size_t)(jb + l15 + g * 512) * KP_CH + k0);
#pragma unroll
        for (int s = 0; s < 4; s++)
#pragma unroll
            for (int g = 0; g < 3; g++)
                gi[s][g] = __builtin_amdgcn_mfma_f32_16x16x32_bf16(a[s], b[g], gi[s][g], 0, 0, 0);
    }

    for (int kb = 0; kb < MEM; kb += 32) {
        int k0 = kb + koff;
        short8 a[4];
#pragma unroll
        for (int s = 0; s < 4; s++) {
            int row = m_blk + s * 16 + l15;
            a[s] = (row < n) ? *(const short8*)(h1b + (size_t)row * MEM + k0) : z8;
        }
        short8 b[3];
#pragma unroll
        for (int g = 0; g < 3; g++)
            b[g] = *(const short8*)(Wh + (size_t)(jb + l15 + g * 512) * MEM + k0);
#pragma unroll
        for (int s = 0; s < 4; s++)
#pragma unroll
            for (int g = 0; g < 3; g++)
                gh[s][g] = __builtin_amdgcn_mfma_f32_16x16x32_bf16(a[s], b[g], gh[s][g], 0, 0, 0);
    }

    int j = jb + l15;
    float bir = biasf[3072 + j], biz = biasf[3584 + j], bin = biasf[4096 + j];
    float bhr = biasf[4608 + j], bhz = biasf[5120 + j], bhn = biasf[5632 + j];
#pragma unroll
    for (int s = 0; s < 4; s++)
#pragma unroll
        for (int r = 0; r < 4; r++) {
            int m = m_blk + s * 16 + quad * 4 + r;
            if (m >= n) continue;
            float hp = h1f ? h1f[(size_t)m * MEM + j] : b2f(h1b[(size_t)m * MEM + j]);
            float rr = sigm(gi[s][0][r] + bir + gh[s][0][r] + bhr);
            float zz = sigm(gi[s][1][r] + biz + gh[s][1][r] + bhz);
            float nn = tanh_f(gi[s][2][r] + bin + rr * (gh[s][2][r] + bhn));
            float h = (1.0f - zz) * nn + zz * hp;
            h2b[(size_t)m * MEM + j] = f2b(h);
            if (h2f) h2f[(size_t)m * MEM + j] = h;
        }
}

__launch_bounds__(256)
__global__ void gemm_stage3(const unsigned short* __restrict__ h2b,
                            const float* __restrict__ h2f,
                            const unsigned short* __restrict__ Wh,
                            const float* __restrict__ biasf,
                            int n,
                            unsigned short* __restrict__ out,
                            float* __restrict__ outf) {
    int wv = threadIdx.x >> 6, lane = threadIdx.x & 63;
    int l15 = lane & 15, quad = lane >> 4, koff = quad * 8;
    int m_blk = blockIdx.x * 64;
    int jb = blockIdx.y * 64 + wv * 16;

    floatx4 acc[4][3];
#pragma unroll
    for (int s = 0; s < 4; s++)
#pragma unroll
        for (int g = 0; g < 3; g++) acc[s][g] = (floatx4){0.f, 0.f, 0.f, 0.f};
    short8 z8 = {0, 0, 0, 0, 0, 0, 0, 0};

    for (int kb = 0; kb < MEM; kb += 32) {
        int k0 = kb + koff;
        short8 a[4];
#pragma unroll
        for (int s = 0; s < 4; s++) {
            int row = m_blk + s * 16 + l15;
            a[s] = (row < n) ? *(const short8*)(h2b + (size_t)row * MEM + k0) : z8;
        }
        short8 b[3];
#pragma unroll
        for (int g = 0; g < 3; g++)
            b[g] = *(const short8*)(Wh + (size_t)(jb + l15 + g * 512) * MEM + k0);
#pragma unroll
        for (int s = 0; s < 4; s++)
#pragma unroll
            for (int g = 0; g < 3; g++)
                acc[s][g] = __builtin_amdgcn_mfma_f32_16x16x32_bf16(a[s], b[g], acc[s][g], 0, 0, 0);
    }

    int j = jb + l15;
    float gir = biasf[6144 + j], giz = biasf[6656 + j], gin = biasf[7168 + j];
    float bhr = biasf[7680 + j], bhz = biasf[8192 + j], bhn = biasf[8704 + j];
#pragma unroll
    for (int s = 0; s < 4; s++)
#pragma unroll
        for (int r = 0; r < 4; r++) {
            int m = m_blk + s * 16 + quad * 4 + r;
            if (m >= n) continue;
            float hp = h2f ? h2f[(size_t)m * MEM + j] : b2f(h2b[(size_t)m * MEM + j]);
            float rr = sigm(gir + acc[s][0][r] + bhr);
            float zz = sigm(giz + acc[s][1][r] + bhz);
            float nn = tanh_f(gin + rr * (acc[s][2][r] + bhn));
            float h = (1.0f - zz) * nn + zz * hp;
            out[(size_t)m * MEM + j] = f2b(h);
            if (outf) outf[(size_t)m * MEM + j] = h;
        }
}

__global__ void copy_out_kernel(const int* __restrict__ flag,
                                const unsigned short* __restrict__ states,
                                const float* __restrict__ rootf,
                                void* __restrict__ out) {
    int j = threadIdx.x;
    if (j >= MEM) return;
    if (*flag) ((float*)out)[j] = rootf[j];
    else ((unsigned short*)out)[j] = states[j];
}

// ---------------- launch ----------------

extern "C" void kernel_launch(void* const* d_in, const int* in_sizes, int n_in,
                              void* d_out, int out_size, void* d_ws, size_t ws_size,
                              hipStream_t stream) {
    const void* embs    = d_in[0];
    const void* tags    = d_in[1];
    const void* leaf_Wi = d_in[2];
    const void* leaf_bi = d_in[4];
    const void* leaf_bh = d_in[5];
    const void* node_Wh = d_in[7];
    const void* node_bi = d_in[8];
    const void* node_bh = d_in[9];
    const void* ch_Wi   = d_in[10];
    const void* ch_Wh   = d_in[11];
    const void* ch_bi   = d_in[12];
    const void* ch_bh   = d_in[13];
    (void)in_sizes; (void)n_in; (void)out_size;

    char* ws = (char*)d_ws;
    const size_t o_flag   = 0;
    const size_t o_bias   = 256;
    const size_t o_Wl     = o_bias + 36864;
    const size_t o_Wc     = o_Wl + (size_t)1536 * KP_LEAF * 2;
    const size_t o_Whc    = o_Wc + (size_t)1536 * KP_CH * 2;
    const size_t o_Whn    = o_Whc + (size_t)1536 * MEM * 2;
    const size_t o_states = o_Whn + (size_t)1536 * MEM * 2;
    const size_t o_T2     = o_states + (size_t)32768 * MEM * 2;
    const size_t o_h1b    = o_T2 + (size_t)32768 * T2W * 2;
    const size_t o_h2b    = o_h1b + (size_t)8192 * MEM * 2;
    const size_t o_rootf  = o_h2b + (size_t)8192 * MEM * 2;
    const size_t o_h1f    = o_rootf + 2048;
    const size_t o_h2f    = o_h1f + (size_t)8192 * MEM * 4;
    const size_t NEED0    = o_h2f + (size_t)8192 * MEM * 4;   // ~105 MB

    bool tier0 = (ws_size >= NEED0);

    int*            flag   = (int*)(ws + o_flag);
    float*          biasf  = (float*)(ws + o_bias);
    unsigned short* Wl     = (unsigned short*)(ws + o_Wl);
    unsigned short* Wc     = (unsigned short*)(ws + o_Wc);
    unsigned short* Whc    = (unsigned short*)(ws + o_Whc);
    unsigned short* Whn    = (unsigned short*)(ws + o_Whn);
    unsigned short* states = (unsigned short*)(ws + o_states);
    unsigned short* T2all  = (unsigned short*)(ws + o_T2);
    unsigned short* h1b    = (unsigned short*)(ws + o_h1b);
    unsigned short* h2b    = (unsigned short*)(ws + o_h2b);
    float*          rootf  = (float*)(ws + o_rootf);
    float*          h1f    = tier0 ? (float*)(ws + o_h1f) : nullptr;
    float*          h2f    = tier0 ? (float*)(ws + o_h2f) : nullptr;
    // Xleaf (13.63 MB) overlays h1b+h2b (16.78 MB): dead before lvl-13 stage1
    unsigned short* Xleaf  = (unsigned short*)(ws + o_h1b);

    init_flag_kernel<<<1, 64, 0, stream>>>(flag);
    detect_kernel<<<2048, 256, 0, stream>>>((const unsigned short*)embs,
                                            (const unsigned short*)ch_Wi, flag);
    convert_kernel<<<2048, 256, 0, stream>>>(flag, leaf_Wi, ch_Wi, ch_Wh, node_Wh,
                                             leaf_bi, leaf_bh, ch_bi, ch_bh,
                                             node_bi, node_bh,
                                             Wl, Wc, Whc, Whn, biasf);
    pack_t2_all_kernel<<<2048, 256, 0, stream>>>(flag, tags, T2all);
    pack_xleaf_kernel<<<2048, 256, 0, stream>>>(flag, embs, tags, Xleaf);

    big3<0><<<(LEAVES / 128) * 8, 512, 0, stream>>>(
        states, T2all, Xleaf, Wl, Wc, Whc, Whn, h1b, h1f, h2b, h2f, biasf,
        LEAVES, states + (size_t)(LEAVES - 1) * MEM, nullptr);

#define LAUNCH_BIG3(M, OB, OF) \
    big3<M><<<(n / 128) * 8, 512, 0, stream>>>( \
        states, T2l, nullptr, Wl, Wc, Whc, Whn, h1b, h1f, h2b, h2f, biasf, n, OB, OF)
#define LAUNCH_BIG2(M, S, OB, OF) \
    big2<M, S><<<dim3(n / (64 * S), 32), 256, 0, stream>>>( \
        states, T2l, nullptr, Wl, Wc, Whc, Whn, h1b, h1f, h2b, h2f, biasf, n, OB, OF)

    for (int lvl = TREE_DEPTH - 1; lvl >= 0; lvl--) {
        int n = 1 << lvl;
        const unsigned short* T2l = T2all + (size_t)(32768 - 4 * n) * T2W;
        unsigned short* st_out = states + (size_t)(n - 1) * MEM;

        if (n >= 2048) {
            LAUNCH_BIG3(1, h1b, h1f);
            LAUNCH_BIG3(2, h2b, h2f);
            LAUNCH_BIG3(3, st_out, nullptr);
        } else if (n >= 1024) {
            LAUNCH_BIG2(1, 2, h1b, h1f);
            LAUNCH_BIG2(2, 2, h2b, h2f);
            LAUNCH_BIG2(3, 2, st_out, nullptr);
        } else if (n >= 128) {
            LAUNCH_BIG2(1, 1, h1b, h1f);
            LAUNCH_BIG2(2, 1, h2b, h2f);
            LAUNCH_BIG2(3, 1, st_out, nullptr);
        } else {
            dim3 g((n + 63) / 64, 8);
            gemm_stage1<<<g, 256, 0, stream>>>(states, T2l, Wc, biasf, n, h1b, h1f);
            gemm_stage2<<<g, 256, 0, stream>>>(states, T2l, Wc, h1b, h1f, Whc, biasf,
                                               n, h2b, h2f);
            gemm_stage3<<<g, 256, 0, stream>>>(h2b, h2f, Whn, biasf, n, st_out,
                                               (n == 1) ? rootf : nullptr);
        }
    }

    copy_out_kernel<<<1, 512, 0, stream>>>(flag, states, rootf, d_out);
}